// Round 13
// baseline (106.808 us; speedup 1.0000x reference)
//
#include <hip/hip_runtime.h>

// x: (2,64,32,32,32) f32; N = 2048 rows of (C=64, L=32)
// qkv(f16): [b][och][32768]; oraw(f16): (N,128,32)
// MFMA convention (validated r3-r11): mfma_f32_32x32x16_f16(A,B,C):
//   A-frag: lane&31 = row m, k = (e&3)+4*(lane>>5)+8*(e>>2)+16*ks
//   B-frag: lane&31 = col n, same k pattern
//   D: col = lane&31, row = (r&3)+8*(r>>2)+4*(lane>>5)
// Partitioning:
//   k_sim : 1024 blocks x 8 waves, 2 pairs/wave (r8 form, ~22us)
//   k_attn: 1024 blocks x 4 waves, 4 PAIRS/WAVE (r13: eP2/ePv loads shared x4;
//           qk held as packed f16 in regs -- r9-validated numerics)
// r9 lesson: qk global round-trip LOSES to recompute. r12 lesson: cooperative
// launch rejected when LDS/block exceeds pessimistic occupancy model -- avoided.

typedef _Float16 f16;
typedef __attribute__((ext_vector_type(2))) _Float16 f16x2;
typedef __attribute__((ext_vector_type(8))) _Float16 f16x8;
typedef __attribute__((ext_vector_type(16))) float f32x16;

struct U4 { unsigned a[4]; };
union F8 { unsigned u[4]; f16x8 v; };

__device__ __forceinline__ U4 ld4(const unsigned* p) {
    uint4 v = *(const uint4*)p;
    U4 r; r.a[0] = v.x; r.a[1] = v.y; r.a[2] = v.z; r.a[3] = v.w;
    return r;
}
__device__ __forceinline__ f16x2 u2h(unsigned u) { return __builtin_bit_cast(f16x2, u); }

__device__ __forceinline__ float fdot2u(unsigned a, unsigned b, float c) {
#if __has_builtin(__builtin_amdgcn_fdot2)
    return __builtin_amdgcn_fdot2(u2h(a), u2h(b), c, false);
#else
    f16x2 x = u2h(a), y = u2h(b);
    return (float)x.x * (float)y.x + (float)x.y * (float)y.y + c;
#endif
}
__device__ __forceinline__ unsigned pkrtz(float a, float b) {
#if __has_builtin(__builtin_amdgcn_cvt_pkrtz)
    return __builtin_bit_cast(unsigned, __builtin_amdgcn_cvt_pkrtz(a, b));
#else
    f16x2 v; v.x = (f16)a; v.y = (f16)b;
    return __builtin_bit_cast(unsigned, v);
#endif
}
__device__ __forceinline__ unsigned pkmul(unsigned a, unsigned b) {
    f16x2 x = u2h(a), y = u2h(b);
    f16x2 r = x * y;
    return __builtin_bit_cast(unsigned, r);
}

__device__ __forceinline__ float sum16(float v) {
    int x;
    x = __builtin_amdgcn_update_dpp(0, __float_as_int(v), 0x121, 0xF, 0xF, true); v += __int_as_float(x);
    x = __builtin_amdgcn_update_dpp(0, __float_as_int(v), 0x122, 0xF, 0xF, true); v += __int_as_float(x);
    x = __builtin_amdgcn_update_dpp(0, __float_as_int(v), 0x124, 0xF, 0xF, true); v += __int_as_float(x);
    x = __builtin_amdgcn_update_dpp(0, __float_as_int(v), 0x128, 0xF, 0xF, true); v += __int_as_float(x);
    return v;
}
__device__ __forceinline__ float sum32(float v) {
    v = sum16(v); return v + __shfl_xor(v, 16);
}
__device__ __forceinline__ float sum64(float v) {
    v = sum16(v); v += __shfl_xor(v, 16); return v + __shfl_xor(v, 32);
}

// ---------------- K1: qkv = W @ X GEMM via MFMA, LDS-staged ----------------
__global__ __launch_bounds__(256) void k_qkv(const float* __restrict__ x,
                                             const float* __restrict__ w,
                                             f16* __restrict__ qkv,
                                             float* __restrict__ pq) {
    __shared__ __attribute__((aligned(16))) unsigned xt[32 * 66];
    int t = threadIdx.x, wv = t >> 6, l = t & 63;
    int li = l & 31, h = l >> 5;
    int bid = blockIdx.x;
    int b = bid >> 9;
    int col0 = (bid & 511) * 64;
    const float* xb = x + (size_t)b * 2097152 + col0;
    #pragma unroll
    for (int k = 0; k < 4; ++k) {
        int idx = t + 256 * k;
        int col2 = idx & 31, p = idx >> 5;
        const float* r0 = xb + (size_t)(2 * p) * 32768 + 2 * col2;
        float2 a = *(const float2*)r0;
        float2 bb = *(const float2*)(r0 + 32768);
        int ks = p >> 3, hh = (p >> 1) & 1, m = (p & 1) + 2 * ((p >> 2) & 1);
        unsigned w0 = pkrtz(a.x, bb.x);
        unsigned w1 = pkrtz(a.y, bb.y);
        *(uint2*)&xt[(ks * 8 + hh * 4 + m) * 66 + 2 * col2] = make_uint2(w0, w1);
    }
    f16x8 aw[4];
    {
        const float* wr = w + (size_t)(32 * wv + li) * 64;
        #pragma unroll
        for (int ks = 0; ks < 4; ++ks) {
            float4 w0 = *(const float4*)(wr + 16 * ks + 4 * h);
            float4 w1 = *(const float4*)(wr + 16 * ks + 8 + 4 * h);
            F8 fa;
            fa.u[0] = pkrtz(w0.x, w0.y); fa.u[1] = pkrtz(w0.z, w0.w);
            fa.u[2] = pkrtz(w1.x, w1.y); fa.u[3] = pkrtz(w1.z, w1.w);
            aw[ks] = fa.v;
        }
    }
    __syncthreads();
    float s1a[16] = {}, s2a[16] = {};
    #pragma unroll
    for (int ct = 0; ct < 2; ++ct) {
        f32x16 D = {};
        #pragma unroll
        for (int ks = 0; ks < 4; ++ks) {
            F8 fb;
            #pragma unroll
            for (int m = 0; m < 4; ++m)
                fb.u[m] = xt[(ks * 8 + h * 4 + m) * 66 + ct * 32 + li];
            D = __builtin_amdgcn_mfma_f32_32x32x16_f16(aw[ks], fb.v, D, 0, 0, 0);
        }
        int colg = col0 + ct * 32 + li;
        f16* qn = qkv + (size_t)b * 4194304 + colg;
        #pragma unroll
        for (int r = 0; r < 16; ++r) {
            int och = 32 * wv + (r & 3) + 8 * (r >> 2) + 4 * h;
            qn[(size_t)och * 32768] = (f16)D[r];
            s1a[r] += D[r];
            s2a[r] += D[r] * D[r];
        }
    }
    #pragma unroll
    for (int r = 0; r < 16; ++r) {
        float s1 = sum32(s1a[r]);
        float s2 = sum32(s2a[r]);
        if (li == 0) {
            int och = 32 * wv + (r & 3) + 8 * (r >> 2) + 4 * h;
            pq[(size_t)bid * 256 + och * 2] = s1;
            pq[(size_t)bid * 256 + och * 2 + 1] = s2;
        }
    }
}

// ---------------- K1b: reduce qkv-stat partials + build f16 emb tables -------
__global__ __launch_bounds__(256) void red_qkv(const float* __restrict__ pq,
                                               float* __restrict__ sqkv,
                                               const float* __restrict__ rel,
                                               f16* __restrict__ gemb) {
    int t = threadIdx.x;
    int base = blockIdx.x * 64;
    float acc = 0;
    #pragma unroll 8
    for (int k = 0; k < 64; ++k) acc += pq[(size_t)(base + k) * 256 + t];
    atomicAdd(&sqkv[((t & 1) ? 128 : 0) + (t >> 1)], acc);
    int tid = blockIdx.x * 256 + t;
    for (int e = tid; e < 4608; e += 4096) {         // eT2
        int c2 = e / 1152, rm = e % 1152, y = rm / 36, x = rm % 36;
        f16 v0 = (f16)0, v1 = (f16)0;
        if (x < 32) {
            v0 = (f16)rel[(2 * c2) * 63 + x - y + 31];
            v1 = (f16)rel[(2 * c2 + 1) * 63 + x - y + 31];
        }
        gemb[2 * e] = v0; gemb[2 * e + 1] = v1;
    }
    for (int e = tid; e < 4608; e += 4096) {         // eP2 (half offset 9216)
        int c2 = e / 1152, rm = e % 1152, a = rm / 36, b = rm % 36;
        f16 v0 = (f16)0, v1 = (f16)0;
        if (b < 32) {
            v0 = (f16)rel[(2 * c2) * 63 + a - b + 31];
            v1 = (f16)rel[(2 * c2 + 1) * 63 + a - b + 31];
        }
        gemb[9216 + 2 * e] = v0; gemb[9216 + 2 * e + 1] = v1;
    }
    for (int e = tid; e < 9216; e += 4096) {         // ePv (half offset 18432)
        int c = e / 1152, rm = e % 1152, a = rm / 36, b = rm % 36;
        gemb[18432 + e] = (b < 32) ? (f16)rel[(8 + c) * 63 + a - b + 31] : (f16)0;
    }
}

// ---------------- K2: sim stats (r8 form: 512 thr, 1024 blocks) ----------------
__global__ __launch_bounds__(512, 2) void k_sim(const f16* __restrict__ qkv,
                                                const f16* __restrict__ gemb,
                                                const float* __restrict__ sqkv,
                                                const float* __restrict__ bqg,
                                                const float* __restrict__ bqb,
                                                float* __restrict__ psim) {
    __shared__ __attribute__((aligned(16))) f16 qkh[2][8][256];
    __shared__ float statw[8][6];
    int t = threadIdx.x, wv = t >> 6, l = t & 63;
    int g = blockIdx.x & 7, nb = blockIdx.x >> 3;   // nb in [0,128)
    int li = l & 31, h = l >> 5;
    const unsigned* eT2u = (const unsigned*)gemb;
    {
        int ch = l >> 3, i0 = (l & 7) * 4;
        int cc = g * 16 + ch;
        float mu = sqkv[cc] * (1.0f / 65536.0f);
        float var = sqkv[128 + cc] * (1.0f / 65536.0f) - mu * mu;
        float aa = bqg[cc] * rsqrtf(var + 1e-5f);
        float bb = bqb[cc] - mu * aa;
        #pragma unroll
        for (int pr = 0; pr < 2; ++pr) {
            int n = nb * 8 + wv + pr * 1024;
            int b_ = n >> 10, hw = n & 1023;
            const f16* qn = qkv + (size_t)b_ * 4194304 + (size_t)(g * 16) * 32768 + hw * 32;
            uint2 q2 = *(const uint2*)(qn + (size_t)ch * 32768 + i0);
            f16x2 p0 = u2h(q2.x), p1 = u2h(q2.y);
            qkh[pr][wv][(i0 + 0) * 8 + ch] = (f16)(aa * (float)p0.x + bb);
            qkh[pr][wv][(i0 + 1) * 8 + ch] = (f16)(aa * (float)p0.y + bb);
            qkh[pr][wv][(i0 + 2) * 8 + ch] = (f16)(aa * (float)p1.x + bb);
            qkh[pr][wv][(i0 + 3) * 8 + ch] = (f16)(aa * (float)p1.y + bb);
        }
    }
    __syncthreads();
    unsigned uq[2][2][4], uk[2][2][4];
    float sqe = 0, sqe2 = 0, ske = 0, ske2 = 0;
    #pragma unroll
    for (int s = 0; s < 2; ++s) {
        #pragma unroll
        for (int blk = 0; blk < 2; ++blk) {
            int p0 = 16 * s + 4 * h + 8 * blk;
            U4 e0 = ld4(eT2u + 0 * 1152 + li * 36 + p0);
            U4 e1 = ld4(eT2u + 1 * 1152 + li * 36 + p0);
            U4 e2 = ld4(eT2u + 2 * 1152 + li * 36 + p0);
            U4 e3 = ld4(eT2u + 3 * 1152 + li * 36 + p0);
            #pragma unroll
            for (int pr = 0; pr < 2; ++pr) {
                float qe[4], ke[4];
                #pragma unroll
                for (int e = 0; e < 4; ++e) {
                    U4 qr = ld4((const unsigned*)&qkh[pr][wv][(p0 + e) * 8]);
                    qe[e] = fdot2u(qr.a[0], e0.a[e], fdot2u(qr.a[1], e1.a[e], 0.f));
                    ke[e] = fdot2u(qr.a[2], e2.a[e], fdot2u(qr.a[3], e3.a[e], 0.f));
                    sqe += qe[e]; sqe2 += qe[e] * qe[e];
                    ske += ke[e]; ske2 += ke[e] * ke[e];
                }
                uq[pr][s][2 * blk + 0] = pkrtz(qe[0], qe[1]);
                uq[pr][s][2 * blk + 1] = pkrtz(qe[2], qe[3]);
                uk[pr][s][2 * blk + 0] = pkrtz(ke[0], ke[1]);
                uk[pr][s][2 * blk + 1] = pkrtz(ke[2], ke[3]);
            }
        }
    }
    float s1 = 0, s2 = 0;
    #pragma unroll
    for (int pr = 0; pr < 2; ++pr) {
        F8 fq0, fq1, fk0, fk1;
        #pragma unroll
        for (int j = 0; j < 4; ++j) {
            fq0.u[j] = uq[pr][0][j]; fq1.u[j] = uq[pr][1][j];
            fk0.u[j] = uk[pr][0][j]; fk1.u[j] = uk[pr][1][j];
        }
        f32x16 D = {};
        D = __builtin_amdgcn_mfma_f32_32x32x16_f16(fk0.v, fq0.v, D, 0, 0, 0);
        D = __builtin_amdgcn_mfma_f32_32x32x16_f16(fk1.v, fq1.v, D, 0, 0, 0);
        #pragma unroll
        for (int r = 0; r < 16; ++r) { s1 += D[r]; s2 += D[r] * D[r]; }
    }
    s1 = sum64(s1);   s2 = sum64(s2);
    sqe = sum64(sqe); sqe2 = sum64(sqe2);
    ske = sum64(ske); ske2 = sum64(ske2);
    if (l == 0) {
        statw[wv][0] = s1;  statw[wv][1] = s2;
        statw[wv][2] = sqe; statw[wv][3] = sqe2;
        statw[wv][4] = ske; statw[wv][5] = ske2;
    }
    __syncthreads();
    if (t < 6) {
        float tot = 0;
        #pragma unroll
        for (int w2 = 0; w2 < 8; ++w2) tot += statw[w2][t];
        psim[blockIdx.x * 8 + t] = tot;
    }
}

// ---------------- K3: reduce sim partials ----------------
__global__ __launch_bounds__(64) void red_sim(const float* __restrict__ psim,
                                              float* __restrict__ ssim) {
    int t = threadIdx.x;
    if (t >= 48) return;
    int g = t / 6, s = t % 6;
    float acc = 0;
    #pragma unroll 8
    for (int nb = 0; nb < 128; ++nb) acc += psim[(nb * 8 + g) * 8 + s];
    const int base[6] = {0, 24, 8, 32, 16, 40};
    ssim[base[s] + g] = acc;
}

// ---------------- K4: attention, 4 pairs/wave (1024 blocks x 256 thr) ---------
__global__ __launch_bounds__(256, 4) void k_attn(const f16* __restrict__ qkv,
                                                 const f16* __restrict__ gemb,
                                                 const float* __restrict__ sqkv,
                                                 const float* __restrict__ bqg,
                                                 const float* __restrict__ bqb,
                                                 const float* __restrict__ ssim,
                                                 const float* __restrict__ bsg,
                                                 const float* __restrict__ bsb,
                                                 f16* __restrict__ oraw,
                                                 float* __restrict__ sout) {
    __shared__ __attribute__((aligned(16))) f16 qkh[4][4][256];
    __shared__ __attribute__((aligned(16))) f16 vh[4][4][288];
    __shared__ float statw[4][32];
    int t = threadIdx.x, wv = t >> 6, l = t & 63;
    int g = blockIdx.x & 7, nb = blockIdx.x >> 3;   // nb in [0,128)
    int li = l & 31, h = l >> 5;
    const unsigned* eT2u = (const unsigned*)gemb;
    const unsigned* eP2u = eT2u + 4608;
    const f16* ePvh = gemb + 18432;
    int nbase = nb * 4 + wv;                         // [0,512)
    float aQK, aQE, aKE, csum;
    {
        float m0 = ssim[g] * (1.0f / 2097152.0f);
        float v0 = ssim[24 + g] * (1.0f / 2097152.0f) - m0 * m0;
        aQK = bsg[g] * rsqrtf(v0 + 1e-5f);
        float b0 = bsb[g] - m0 * aQK;
        float m1 = ssim[8 + g] * (1.0f / 2097152.0f);
        float v1 = ssim[32 + g] * (1.0f / 2097152.0f) - m1 * m1;
        aQE = bsg[8 + g] * rsqrtf(v1 + 1e-5f);
        float b1 = bsb[8 + g] - m1 * aQE;
        float m2 = ssim[16 + g] * (1.0f / 2097152.0f);
        float v2 = ssim[40 + g] * (1.0f / 2097152.0f) - m2 * m2;
        aKE = bsg[16 + g] * rsqrtf(v2 + 1e-5f);
        float b2 = bsb[16 + g] - m2 * aKE;
        csum = b0 + b1 + b2 - 6.0f;   // -6 bias cancels in softmax, keeps e^s in f16
    }
    {   // stage 4 pairs
        int ch = l >> 3, i0 = (l & 7) * 4;
        int cc = g * 16 + ch;
        float mu = sqkv[cc] * (1.0f / 65536.0f);
        float var = sqkv[128 + cc] * (1.0f / 65536.0f) - mu * mu;
        float aa = bqg[cc] * rsqrtf(var + 1e-5f);
        float bb = bqb[cc] - mu * aa;
        int cv = g * 16 + 8 + ch;
        float muv = sqkv[cv] * (1.0f / 65536.0f);
        float varv = sqkv[128 + cv] * (1.0f / 65536.0f) - muv * muv;
        float av = bqg[cv] * rsqrtf(varv + 1e-5f);
        float bv = bqb[cv] - muv * av;
        #pragma unroll
        for (int pr = 0; pr < 4; ++pr) {
            int n = nbase + pr * 512;
            int b_ = n >> 10, hw = n & 1023;
            const f16* qn = qkv + (size_t)b_ * 4194304 + (size_t)(g * 16) * 32768 + hw * 32;
            uint2 q2 = *(const uint2*)(qn + (size_t)ch * 32768 + i0);
            f16x2 p0 = u2h(q2.x), p1 = u2h(q2.y);
            qkh[pr][wv][(i0 + 0) * 8 + ch] = (f16)(aa * (float)p0.x + bb);
            qkh[pr][wv][(i0 + 1) * 8 + ch] = (f16)(aa * (float)p0.y + bb);
            qkh[pr][wv][(i0 + 2) * 8 + ch] = (f16)(aa * (float)p1.x + bb);
            qkh[pr][wv][(i0 + 3) * 8 + ch] = (f16)(aa * (float)p1.y + bb);
            uint2 v2q = *(const uint2*)(qn + (size_t)(8 + ch) * 32768 + i0);
            f16x2 v0 = u2h(v2q.x), v1q = u2h(v2q.y);
            vh[pr][wv][ch * 36 + i0 + 0] = (f16)(av * (float)v0.x + bv);
            vh[pr][wv][ch * 36 + i0 + 1] = (f16)(av * (float)v0.y + bv);
            vh[pr][wv][ch * 36 + i0 + 2] = (f16)(av * (float)v1q.x + bv);
            vh[pr][wv][ch * 36 + i0 + 3] = (f16)(av * (float)v1q.y + bv);
        }
    }
    __syncthreads();
    // ---- frag + MFMA qk (packed f16 into dqp), groups of 2 pairs ----
    unsigned dqp[4][8];
    #pragma unroll
    for (int grp = 0; grp < 2; ++grp) {
        unsigned uq[2][2][4], uk[2][2][4];
        #pragma unroll
        for (int s = 0; s < 2; ++s) {
            #pragma unroll
            for (int blk = 0; blk < 2; ++blk) {
                int p0 = 16 * s + 4 * h + 8 * blk;
                U4 e0 = ld4(eT2u + 0 * 1152 + li * 36 + p0);
                U4 e1 = ld4(eT2u + 1 * 1152 + li * 36 + p0);
                U4 e2 = ld4(eT2u + 2 * 1152 + li * 36 + p0);
                U4 e3 = ld4(eT2u + 3 * 1152 + li * 36 + p0);
                #pragma unroll
                for (int pi = 0; pi < 2; ++pi) {
                    int pr = 2 * grp + pi;
                    float qe[4], ke[4];
                    #pragma unroll
                    for (int e = 0; e < 4; ++e) {
                        U4 qr = ld4((const unsigned*)&qkh[pr][wv][(p0 + e) * 8]);
                        qe[e] = fdot2u(qr.a[0], e0.a[e], fdot2u(qr.a[1], e1.a[e], 0.f));
                        ke[e] = fdot2u(qr.a[2], e2.a[e], fdot2u(qr.a[3], e3.a[e], 0.f));
                    }
                    uq[pi][s][2 * blk + 0] = pkrtz(qe[0], qe[1]);
                    uq[pi][s][2 * blk + 1] = pkrtz(qe[2], qe[3]);
                    uk[pi][s][2 * blk + 0] = pkrtz(ke[0], ke[1]);
                    uk[pi][s][2 * blk + 1] = pkrtz(ke[2], ke[3]);
                }
            }
        }
        #pragma unroll
        for (int pi = 0; pi < 2; ++pi) {
            int pr = 2 * grp + pi;
            F8 fq0, fq1, fk0, fk1;
            #pragma unroll
            for (int j = 0; j < 4; ++j) {
                fq0.u[j] = uq[pi][0][j]; fq1.u[j] = uq[pi][1][j];
                fk0.u[j] = uk[pi][0][j]; fk1.u[j] = uk[pi][1][j];
            }
            f32x16 D = {};
            D = __builtin_amdgcn_mfma_f32_32x32x16_f16(fk0.v, fq0.v, D, 0, 0, 0);
            D = __builtin_amdgcn_mfma_f32_32x32x16_f16(fk1.v, fq1.v, D, 0, 0, 0);
            #pragma unroll
            for (int rq = 0; rq < 4; ++rq) {
                dqp[pr][2 * rq + 0] = pkrtz(D[4 * rq + 0], D[4 * rq + 1]);
                dqp[pr][2 * rq + 1] = pkrtz(D[4 * rq + 2], D[4 * rq + 3]);
            }
        }
    }
    // ---- scores + softmax: eP2 loads shared across ALL 4 pairs ----
    U4 qhv[4];
    #pragma unroll
    for (int pr = 0; pr < 4; ++pr) qhv[pr] = ld4((const unsigned*)&qkh[pr][wv][li * 8]);
    unsigned up[4][8];
    float se[4] = {};
    const unsigned one2 = 0x3C003C00u;
    #pragma unroll
    for (int rq = 0; rq < 4; ++rq) {
        int j0 = 8 * rq + 4 * h;
        U4 a0 = ld4(eP2u + 0 * 1152 + li * 36 + j0);
        U4 a1 = ld4(eP2u + 1 * 1152 + li * 36 + j0);
        U4 a2 = ld4(eP2u + 2 * 1152 + li * 36 + j0);
        U4 a3 = ld4(eP2u + 3 * 1152 + li * 36 + j0);
        #pragma unroll
        for (int pr = 0; pr < 4; ++pr) {
            f16x2 da = u2h(dqp[pr][2 * rq]), db = u2h(dqp[pr][2 * rq + 1]);
            float qkv4[4] = {(float)da.x, (float)da.y, (float)db.x, (float)db.y};
            float ev[4];
            #pragma unroll
            for (int e = 0; e < 4; ++e) {
                float qe4 = fdot2u(qhv[pr].a[0], a0.a[e], fdot2u(qhv[pr].a[1], a1.a[e], 0.f));
                float ke4 = fdot2u(qhv[pr].a[2], a2.a[e], fdot2u(qhv[pr].a[3], a3.a[e], 0.f));
                ev[e] = __expf(aQK * qkv4[e] + aQE * qe4 + aKE * ke4 + csum);
            }
            up[pr][2 * rq] = pkrtz(ev[0], ev[1]);
            up[pr][2 * rq + 1] = pkrtz(ev[2], ev[3]);
            se[pr] = fdot2u(up[pr][2 * rq], one2, se[pr]);
            se[pr] = fdot2u(up[pr][2 * rq + 1], one2, se[pr]);
        }
    }
    #pragma unroll
    for (int pr = 0; pr < 4; ++pr) {
        float s = se[pr] + __shfl_xor(se[pr], 32);
        float iv = __frcp_rn(s);
        unsigned hiv = pkrtz(iv, iv);
        #pragma unroll
        for (int w2 = 0; w2 < 8; ++w2) up[pr][w2] = pkmul(up[pr][w2], hiv);
    }
    // ---- PV via MFMA per pair (only D[0..3] live: rows c = e + 4h) ----
    float avr[4][4];
    #pragma unroll
    for (int pr = 0; pr < 4; ++pr) {
        F8 fp0, fp1, fv0, fv1;
        fp0.u[0] = up[pr][0]; fp0.u[1] = up[pr][1]; fp0.u[2] = up[pr][2]; fp0.u[3] = up[pr][3];
        fp1.u[0] = up[pr][4]; fp1.u[1] = up[pr][5]; fp1.u[2] = up[pr][6]; fp1.u[3] = up[pr][7];
        const f16* vb = &vh[pr][wv][(li & 7) * 36];
        uint2 va0 = *(const uint2*)(vb + 4 * h);
        uint2 vb0 = *(const uint2*)(vb + 4 * h + 8);
        uint2 va1 = *(const uint2*)(vb + 16 + 4 * h);
        uint2 vb1 = *(const uint2*)(vb + 16 + 4 * h + 8);
        if (li >= 8) {
            va0 = make_uint2(0, 0); vb0 = make_uint2(0, 0);
            va1 = make_uint2(0, 0); vb1 = make_uint2(0, 0);
        }
        fv0.u[0] = va0.x; fv0.u[1] = va0.y; fv0.u[2] = vb0.x; fv0.u[3] = vb0.y;
        fv1.u[0] = va1.x; fv1.u[1] = va1.y; fv1.u[2] = vb1.x; fv1.u[3] = vb1.y;
        f32x16 D2 = {};
        D2 = __builtin_amdgcn_mfma_f32_32x32x16_f16(fv0.v, fp0.v, D2, 0, 0, 0);
        D2 = __builtin_amdgcn_mfma_f32_32x32x16_f16(fv1.v, fp1.v, D2, 0, 0, 0);
        avr[pr][0] = D2[0]; avr[pr][1] = D2[1]; avr[pr][2] = D2[2]; avr[pr][3] = D2[3];
    }
    // ---- ame via dot2: ePv loads shared across ALL 4 pairs ----
    float ame[4][8];
    #pragma unroll
    for (int c = 0; c < 8; ++c) {
        const f16* er = ePvh + (c * 32 + li) * 36;
        float ac[4] = {};
        #pragma unroll
        for (int s = 0; s < 2; ++s) {
            #pragma unroll
            for (int dd = 0; dd < 2; ++dd) {
                uint2 ev = *(const uint2*)(er + 16 * s + 8 * dd + 4 * h);
                int widx = 4 * s + 2 * dd;
                #pragma unroll
                for (int pr = 0; pr < 4; ++pr) {
                    ac[pr] = fdot2u(up[pr][widx], ev.x, ac[pr]);
                    ac[pr] = fdot2u(up[pr][widx + 1], ev.y, ac[pr]);
                }
            }
        }
        #pragma unroll
        for (int pr = 0; pr < 4; ++pr) ame[pr][c] = ac[pr] + __shfl_xor(ac[pr], 32);
    }
    // ---- write oraw + combined out stats over 4 pairs ----
    float osx1[4] = {}, osx2[4] = {}, osy1[4] = {}, osy2[4] = {};
    #pragma unroll
    for (int pr = 0; pr < 4; ++pr) {
        int n = nbase + pr * 512;
        f16* on = oraw + (size_t)n * 4096 + g * 512;
        #pragma unroll
        for (int e = 0; e < 4; ++e) {
            int c = e + 4 * h;
            float av = avr[pr][e];
            float ae = ame[pr][c];
            on[(2 * c) * 32 + li] = (f16)av;
            on[(2 * c + 1) * 32 + li] = (f16)ae;
            osx1[e] += av; osx2[e] += av * av;
            osy1[e] += ae; osy2[e] += ae * ae;
        }
    }
    #pragma unroll
    for (int e = 0; e < 4; ++e) {
        int c = e + 4 * h;
        float x1 = sum32(osx1[e]), x2 = sum32(osx2[e]);
        float y1 = sum32(osy1[e]), y2 = sum32(osy2[e]);
        if (li == 0) {
            statw[wv][(2 * c) * 2 + 0] = x1;     statw[wv][(2 * c) * 2 + 1] = x2;
            statw[wv][(2 * c + 1) * 2 + 0] = y1; statw[wv][(2 * c + 1) * 2 + 1] = y2;
        }
    }
    __syncthreads();
    if (t < 32) {
        float tot = statw[0][t] + statw[1][t] + statw[2][t] + statw[3][t];
        int u = t >> 1;
        int och = g * 16 + u;
        atomicAdd(&sout[((t & 1) ? 128 : 0) + och], tot);
    }
}

// ---------------- K5: out BN + pair-sum + transpose ----------------
__global__ __launch_bounds__(256) void k_out(const f16* __restrict__ oraw,
                                             const float* __restrict__ sout,
                                             const float* __restrict__ bog,
                                             const float* __restrict__ bob,
                                             float* __restrict__ out) {
    int gid = blockIdx.x * 256 + threadIdx.x;
    int l4 = gid & 7;
    int rest = gid >> 3;
    int w2 = rest & 31; rest >>= 5;
    int hh = rest & 31; rest >>= 5;
    int oc = rest & 63;
    int b = rest >> 6;
    int n = b * 1024 + hh * 32 + w2;
    int c0 = 2 * oc, c1 = 2 * oc + 1;
    float mu0 = sout[c0] * (1.0f / 65536.0f);
    float v0 = sout[128 + c0] * (1.0f / 65536.0f) - mu0 * mu0;
    float a0 = bog[c0] * rsqrtf(v0 + 1e-5f);
    float b0 = bob[c0] - mu0 * a0;
    float mu1 = sout[c1] * (1.0f / 65536.0f);
    float v1 = sout[128 + c1] * (1.0f / 65536.0f) - mu1 * mu1;
    float a1 = bog[c1] * rsqrtf(v1 + 1e-5f);
    float b1 = bob[c1] - mu1 * a1;
    float cc = b0 + b1;
    const f16* on = oraw + (size_t)n * 4096;
    uint2 r0 = *(const uint2*)(on + oc * 64 + l4 * 4);
    uint2 r1 = *(const uint2*)(on + oc * 64 + 32 + l4 * 4);
    f16x2 r0a = u2h(r0.x), r0b = u2h(r0.y);
    f16x2 r1a = u2h(r1.x), r1b = u2h(r1.y);
    float4 o;
    o.x = a0 * (float)r0a.x + a1 * (float)r1a.x + cc;
    o.y = a0 * (float)r0a.y + a1 * (float)r1a.y + cc;
    o.z = a0 * (float)r0b.x + a1 * (float)r1b.x + cc;
    o.w = a0 * (float)r0b.y + a1 * (float)r1b.y + cc;
    *((float4*)out + gid) = o;
}

extern "C" void kernel_launch(void* const* d_in, const int* in_sizes, int n_in,
                              void* d_out, int out_size, void* d_ws, size_t ws_size,
                              hipStream_t stream) {
    const float* x   = (const float*)d_in[0];
    const float* w   = (const float*)d_in[1];
    const float* bqg = (const float*)d_in[2];
    const float* bqb = (const float*)d_in[3];
    const float* bsg = (const float*)d_in[4];
    const float* bsb = (const float*)d_in[5];
    const float* bog = (const float*)d_in[6];
    const float* bob = (const float*)d_in[7];
    const float* rel = (const float*)d_in[8];

    f16* qkv16  = (f16*)d_ws;                       // 16 MB (8,388,608 halves)
    f16* oraw16 = qkv16 + 8388608;                  // 16 MB
    f16* gemb   = oraw16 + 8388608;                 // 55 KB (27,648 halves)
    float* stats = (float*)(gemb + 27648);
    float* sqkv = stats;        // 256
    float* ssim = stats + 256;  // 48
    float* sout = stats + 304;  // 256
    float* pq   = stats + 576;                      // 1 MB (1024*256 f32)
    float* psim = (float*)oraw16;   // overlap: consumed by red_sim before k_attn writes oraw

    hipMemsetAsync(stats, 0, 560 * sizeof(float), stream);

    k_qkv<<<1024, 256, 0, stream>>>(x, w, qkv16, pq);
    red_qkv<<<16, 256, 0, stream>>>(pq, sqkv, rel, gemb);
    k_sim<<<1024, 512, 0, stream>>>(qkv16, gemb, sqkv, bqg, bqb, psim);
    red_sim<<<1, 64, 0, stream>>>(psim, ssim);
    k_attn<<<1024, 256, 0, stream>>>(qkv16, gemb, sqkv, bqg, bqb, ssim, bsg, bsb, oraw16, sout);
    k_out<<<4096, 256, 0, stream>>>(oraw16, sout, bog, bob, (float*)d_out);
}

// Round 14
// 92.052 us; speedup vs baseline: 1.1603x; 1.1603x over previous
//
#include <hip/hip_runtime.h>

// x: (2,64,32,32,32) f32; N = 2048 rows of (C=64, L=32)
// qkv(f16): [b][och][32768]; oraw(f16): (N,128,32)
// MFMA convention (validated r3-r13): mfma_f32_32x32x16_f16(A,B,C):
//   A-frag: lane&31 = row m, k = (e&3)+4*(lane>>5)+8*(e>>2)+16*ks
//   B-frag: lane&31 = col n, same k pattern
//   D: col = lane&31, row = (r&3)+8*(r>>2)+4*(lane>>5)
// Partitioning (r11 proven): k_sim 1024x512 2pair/wave; k_attn 2048x256 2pair/wave.
// r14: table reads COALESCED -- the eT2/eP2 tables are each other's transposes
// (eP2[c][a][b]=rel[a-b+31]=eT2^T), so frag phase reads the eP2 region
// column-wise (b32 at (p0+e)*36+li, lane-consecutive) and score phase reads
// the eT2 region column-wise. Same values, 16x fewer cacheline touches.
// r9: qk round-trip loses to recompute. r12: coop-launch occupancy trap.
// r13: >2 pairs/wave spills (FETCH/WRITE blowup at VGPR 64).

typedef _Float16 f16;
typedef __attribute__((ext_vector_type(2))) _Float16 f16x2;
typedef __attribute__((ext_vector_type(8))) _Float16 f16x8;
typedef __attribute__((ext_vector_type(16))) float f32x16;

struct U4 { unsigned a[4]; };
union F8 { unsigned u[4]; f16x8 v; };

__device__ __forceinline__ U4 ld4(const unsigned* p) {
    uint4 v = *(const uint4*)p;
    U4 r; r.a[0] = v.x; r.a[1] = v.y; r.a[2] = v.z; r.a[3] = v.w;
    return r;
}
__device__ __forceinline__ f16x2 u2h(unsigned u) { return __builtin_bit_cast(f16x2, u); }

__device__ __forceinline__ float fdot2u(unsigned a, unsigned b, float c) {
#if __has_builtin(__builtin_amdgcn_fdot2)
    return __builtin_amdgcn_fdot2(u2h(a), u2h(b), c, false);
#else
    f16x2 x = u2h(a), y = u2h(b);
    return (float)x.x * (float)y.x + (float)x.y * (float)y.y + c;
#endif
}
__device__ __forceinline__ unsigned pkrtz(float a, float b) {
#if __has_builtin(__builtin_amdgcn_cvt_pkrtz)
    return __builtin_bit_cast(unsigned, __builtin_amdgcn_cvt_pkrtz(a, b));
#else
    f16x2 v; v.x = (f16)a; v.y = (f16)b;
    return __builtin_bit_cast(unsigned, v);
#endif
}
__device__ __forceinline__ unsigned pkmul(unsigned a, unsigned b) {
    f16x2 x = u2h(a), y = u2h(b);
    f16x2 r = x * y;
    return __builtin_bit_cast(unsigned, r);
}

__device__ __forceinline__ float sum16(float v) {
    int x;
    x = __builtin_amdgcn_update_dpp(0, __float_as_int(v), 0x121, 0xF, 0xF, true); v += __int_as_float(x);
    x = __builtin_amdgcn_update_dpp(0, __float_as_int(v), 0x122, 0xF, 0xF, true); v += __int_as_float(x);
    x = __builtin_amdgcn_update_dpp(0, __float_as_int(v), 0x124, 0xF, 0xF, true); v += __int_as_float(x);
    x = __builtin_amdgcn_update_dpp(0, __float_as_int(v), 0x128, 0xF, 0xF, true); v += __int_as_float(x);
    return v;
}
__device__ __forceinline__ float sum32(float v) {
    v = sum16(v); return v + __shfl_xor(v, 16);
}
__device__ __forceinline__ float sum64(float v) {
    v = sum16(v); v += __shfl_xor(v, 16); return v + __shfl_xor(v, 32);
}

// ---------------- K1: qkv = W @ X GEMM via MFMA, LDS-staged ----------------
__global__ __launch_bounds__(256) void k_qkv(const float* __restrict__ x,
                                             const float* __restrict__ w,
                                             f16* __restrict__ qkv,
                                             float* __restrict__ pq) {
    __shared__ __attribute__((aligned(16))) unsigned xt[32 * 66];
    int t = threadIdx.x, wv = t >> 6, l = t & 63;
    int li = l & 31, h = l >> 5;
    int bid = blockIdx.x;
    int b = bid >> 9;
    int col0 = (bid & 511) * 64;
    const float* xb = x + (size_t)b * 2097152 + col0;
    #pragma unroll
    for (int k = 0; k < 4; ++k) {
        int idx = t + 256 * k;
        int col2 = idx & 31, p = idx >> 5;
        const float* r0 = xb + (size_t)(2 * p) * 32768 + 2 * col2;
        float2 a = *(const float2*)r0;
        float2 bb = *(const float2*)(r0 + 32768);
        int ks = p >> 3, hh = (p >> 1) & 1, m = (p & 1) + 2 * ((p >> 2) & 1);
        unsigned w0 = pkrtz(a.x, bb.x);
        unsigned w1 = pkrtz(a.y, bb.y);
        *(uint2*)&xt[(ks * 8 + hh * 4 + m) * 66 + 2 * col2] = make_uint2(w0, w1);
    }
    f16x8 aw[4];
    {
        const float* wr = w + (size_t)(32 * wv + li) * 64;
        #pragma unroll
        for (int ks = 0; ks < 4; ++ks) {
            float4 w0 = *(const float4*)(wr + 16 * ks + 4 * h);
            float4 w1 = *(const float4*)(wr + 16 * ks + 8 + 4 * h);
            F8 fa;
            fa.u[0] = pkrtz(w0.x, w0.y); fa.u[1] = pkrtz(w0.z, w0.w);
            fa.u[2] = pkrtz(w1.x, w1.y); fa.u[3] = pkrtz(w1.z, w1.w);
            aw[ks] = fa.v;
        }
    }
    __syncthreads();
    float s1a[16] = {}, s2a[16] = {};
    #pragma unroll
    for (int ct = 0; ct < 2; ++ct) {
        f32x16 D = {};
        #pragma unroll
        for (int ks = 0; ks < 4; ++ks) {
            F8 fb;
            #pragma unroll
            for (int m = 0; m < 4; ++m)
                fb.u[m] = xt[(ks * 8 + h * 4 + m) * 66 + ct * 32 + li];
            D = __builtin_amdgcn_mfma_f32_32x32x16_f16(aw[ks], fb.v, D, 0, 0, 0);
        }
        int colg = col0 + ct * 32 + li;
        f16* qn = qkv + (size_t)b * 4194304 + colg;
        #pragma unroll
        for (int r = 0; r < 16; ++r) {
            int och = 32 * wv + (r & 3) + 8 * (r >> 2) + 4 * h;
            qn[(size_t)och * 32768] = (f16)D[r];
            s1a[r] += D[r];
            s2a[r] += D[r] * D[r];
        }
    }
    #pragma unroll
    for (int r = 0; r < 16; ++r) {
        float s1 = sum32(s1a[r]);
        float s2 = sum32(s2a[r]);
        if (li == 0) {
            int och = 32 * wv + (r & 3) + 8 * (r >> 2) + 4 * h;
            pq[(size_t)bid * 256 + och * 2] = s1;
            pq[(size_t)bid * 256 + och * 2 + 1] = s2;
        }
    }
}

// ---------------- K1b: reduce qkv-stat partials + build f16 emb tables -------
__global__ __launch_bounds__(256) void red_qkv(const float* __restrict__ pq,
                                               float* __restrict__ sqkv,
                                               const float* __restrict__ rel,
                                               f16* __restrict__ gemb) {
    int t = threadIdx.x;
    int base = blockIdx.x * 64;
    float acc = 0;
    #pragma unroll 8
    for (int k = 0; k < 64; ++k) acc += pq[(size_t)(base + k) * 256 + t];
    atomicAdd(&sqkv[((t & 1) ? 128 : 0) + (t >> 1)], acc);
    int tid = blockIdx.x * 256 + t;
    for (int e = tid; e < 4608; e += 4096) {         // eT2 [c2][y][x]=rel[x-y+31]
        int c2 = e / 1152, rm = e % 1152, y = rm / 36, x = rm % 36;
        f16 v0 = (f16)0, v1 = (f16)0;
        if (x < 32) {
            v0 = (f16)rel[(2 * c2) * 63 + x - y + 31];
            v1 = (f16)rel[(2 * c2 + 1) * 63 + x - y + 31];
        }
        gemb[2 * e] = v0; gemb[2 * e + 1] = v1;
    }
    for (int e = tid; e < 4608; e += 4096) {         // eP2 [c2][a][b]=rel[a-b+31]
        int c2 = e / 1152, rm = e % 1152, a = rm / 36, b = rm % 36;
        f16 v0 = (f16)0, v1 = (f16)0;
        if (b < 32) {
            v0 = (f16)rel[(2 * c2) * 63 + a - b + 31];
            v1 = (f16)rel[(2 * c2 + 1) * 63 + a - b + 31];
        }
        gemb[9216 + 2 * e] = v0; gemb[9216 + 2 * e + 1] = v1;
    }
    for (int e = tid; e < 9216; e += 4096) {         // ePv (half offset 18432)
        int c = e / 1152, rm = e % 1152, a = rm / 36, b = rm % 36;
        gemb[18432 + e] = (b < 32) ? (f16)rel[(8 + c) * 63 + a - b + 31] : (f16)0;
    }
}

// ---------------- K2: sim stats (512 thr, 1024 blocks; coalesced tables) ------
__global__ __launch_bounds__(512, 2) void k_sim(const f16* __restrict__ qkv,
                                                const f16* __restrict__ gemb,
                                                const float* __restrict__ sqkv,
                                                const float* __restrict__ bqg,
                                                const float* __restrict__ bqb,
                                                float* __restrict__ psim) {
    __shared__ __attribute__((aligned(16))) f16 qkh[2][8][256];
    __shared__ float statw[8][6];
    int t = threadIdx.x, wv = t >> 6, l = t & 63;
    int g = blockIdx.x & 7, nb = blockIdx.x >> 3;   // nb in [0,128)
    int li = l & 31, h = l >> 5;
    // frag tables read from the eP2 region (== eT2 transposed): coalesced b32
    const unsigned* eTf = (const unsigned*)gemb + 4608;
    {
        int ch = l >> 3, i0 = (l & 7) * 4;
        int cc = g * 16 + ch;
        float mu = sqkv[cc] * (1.0f / 65536.0f);
        float var = sqkv[128 + cc] * (1.0f / 65536.0f) - mu * mu;
        float aa = bqg[cc] * rsqrtf(var + 1e-5f);
        float bb = bqb[cc] - mu * aa;
        #pragma unroll
        for (int pr = 0; pr < 2; ++pr) {
            int n = nb * 8 + wv + pr * 1024;
            int b_ = n >> 10, hw = n & 1023;
            const f16* qn = qkv + (size_t)b_ * 4194304 + (size_t)(g * 16) * 32768 + hw * 32;
            uint2 q2 = *(const uint2*)(qn + (size_t)ch * 32768 + i0);
            f16x2 p0 = u2h(q2.x), p1 = u2h(q2.y);
            qkh[pr][wv][(i0 + 0) * 8 + ch] = (f16)(aa * (float)p0.x + bb);
            qkh[pr][wv][(i0 + 1) * 8 + ch] = (f16)(aa * (float)p0.y + bb);
            qkh[pr][wv][(i0 + 2) * 8 + ch] = (f16)(aa * (float)p1.x + bb);
            qkh[pr][wv][(i0 + 3) * 8 + ch] = (f16)(aa * (float)p1.y + bb);
        }
    }
    __syncthreads();
    unsigned uq[2][2][4], uk[2][2][4];
    float sqe = 0, sqe2 = 0, ske = 0, ske2 = 0;
    #pragma unroll
    for (int s = 0; s < 2; ++s) {
        #pragma unroll
        for (int blk = 0; blk < 2; ++blk) {
            int p0 = 16 * s + 4 * h + 8 * blk;
            unsigned tq0[4], tq1[4], tk0[4], tk1[4];
            #pragma unroll
            for (int e = 0; e < 4; ++e) {             // coalesced: stride-1 in li
                int rowo = (p0 + e) * 36 + li;
                tq0[e] = eTf[0 * 1152 + rowo];
                tq1[e] = eTf[1 * 1152 + rowo];
                tk0[e] = eTf[2 * 1152 + rowo];
                tk1[e] = eTf[3 * 1152 + rowo];
            }
            #pragma unroll
            for (int pr = 0; pr < 2; ++pr) {
                float qe[4], ke[4];
                #pragma unroll
                for (int e = 0; e < 4; ++e) {
                    U4 qr = ld4((const unsigned*)&qkh[pr][wv][(p0 + e) * 8]);
                    qe[e] = fdot2u(qr.a[0], tq0[e], fdot2u(qr.a[1], tq1[e], 0.f));
                    ke[e] = fdot2u(qr.a[2], tk0[e], fdot2u(qr.a[3], tk1[e], 0.f));
                    sqe += qe[e]; sqe2 += qe[e] * qe[e];
                    ske += ke[e]; ske2 += ke[e] * ke[e];
                }
                uq[pr][s][2 * blk + 0] = pkrtz(qe[0], qe[1]);
                uq[pr][s][2 * blk + 1] = pkrtz(qe[2], qe[3]);
                uk[pr][s][2 * blk + 0] = pkrtz(ke[0], ke[1]);
                uk[pr][s][2 * blk + 1] = pkrtz(ke[2], ke[3]);
            }
        }
    }
    float s1 = 0, s2 = 0;
    #pragma unroll
    for (int pr = 0; pr < 2; ++pr) {
        F8 fq0, fq1, fk0, fk1;
        #pragma unroll
        for (int j = 0; j < 4; ++j) {
            fq0.u[j] = uq[pr][0][j]; fq1.u[j] = uq[pr][1][j];
            fk0.u[j] = uk[pr][0][j]; fk1.u[j] = uk[pr][1][j];
        }
        f32x16 D = {};
        D = __builtin_amdgcn_mfma_f32_32x32x16_f16(fk0.v, fq0.v, D, 0, 0, 0);
        D = __builtin_amdgcn_mfma_f32_32x32x16_f16(fk1.v, fq1.v, D, 0, 0, 0);
        #pragma unroll
        for (int r = 0; r < 16; ++r) { s1 += D[r]; s2 += D[r] * D[r]; }
    }
    s1 = sum64(s1);   s2 = sum64(s2);
    sqe = sum64(sqe); sqe2 = sum64(sqe2);
    ske = sum64(ske); ske2 = sum64(ske2);
    if (l == 0) {
        statw[wv][0] = s1;  statw[wv][1] = s2;
        statw[wv][2] = sqe; statw[wv][3] = sqe2;
        statw[wv][4] = ske; statw[wv][5] = ske2;
    }
    __syncthreads();
    if (t < 6) {
        float tot = 0;
        #pragma unroll
        for (int w2 = 0; w2 < 8; ++w2) tot += statw[w2][t];
        psim[blockIdx.x * 8 + t] = tot;
    }
}

// ---------------- K3: reduce sim partials ----------------
__global__ __launch_bounds__(64) void red_sim(const float* __restrict__ psim,
                                              float* __restrict__ ssim) {
    int t = threadIdx.x;
    if (t >= 48) return;
    int g = t / 6, s = t % 6;
    float acc = 0;
    #pragma unroll 8
    for (int nb = 0; nb < 128; ++nb) acc += psim[(nb * 8 + g) * 8 + s];
    const int base[6] = {0, 24, 8, 32, 16, 40};
    ssim[base[s] + g] = acc;
}

// ---------------- K4: attention (2048 x 256, 2 pairs/wave, coalesced tables) --
__global__ __launch_bounds__(256, 4) void k_attn(const f16* __restrict__ qkv,
                                                 const f16* __restrict__ gemb,
                                                 const float* __restrict__ sqkv,
                                                 const float* __restrict__ bqg,
                                                 const float* __restrict__ bqb,
                                                 const float* __restrict__ ssim,
                                                 const float* __restrict__ bsg,
                                                 const float* __restrict__ bsb,
                                                 f16* __restrict__ oraw,
                                                 float* __restrict__ sout) {
    __shared__ __attribute__((aligned(16))) f16 qkh[2][4][256];
    __shared__ __attribute__((aligned(16))) f16 vh[2][4][288];
    __shared__ float statw[4][32];
    int t = threadIdx.x, wv = t >> 6, l = t & 63;
    int g = blockIdx.x & 7, nb = blockIdx.x >> 3;   // nb in [0,256)
    int li = l & 31, h = l >> 5;
    const unsigned* eTf = (const unsigned*)gemb + 4608;  // frag: eP2 region (transposed read)
    const unsigned* eSc = (const unsigned*)gemb;         // score: eT2 region (transposed read)
    const f16* ePvh = gemb + 18432;
    int n0 = nb * 4 + wv, n1 = n0 + 1024;
    float aQK, aQE, aKE, csum;
    {
        float m0 = ssim[g] * (1.0f / 2097152.0f);
        float v0 = ssim[24 + g] * (1.0f / 2097152.0f) - m0 * m0;
        aQK = bsg[g] * rsqrtf(v0 + 1e-5f);
        float b0 = bsb[g] - m0 * aQK;
        float m1 = ssim[8 + g] * (1.0f / 2097152.0f);
        float v1 = ssim[32 + g] * (1.0f / 2097152.0f) - m1 * m1;
        aQE = bsg[8 + g] * rsqrtf(v1 + 1e-5f);
        float b1 = bsb[8 + g] - m1 * aQE;
        float m2 = ssim[16 + g] * (1.0f / 2097152.0f);
        float v2 = ssim[40 + g] * (1.0f / 2097152.0f) - m2 * m2;
        aKE = bsg[16 + g] * rsqrtf(v2 + 1e-5f);
        float b2 = bsb[16 + g] - m2 * aKE;
        csum = b0 + b1 + b2 - 6.0f;   // -6 bias cancels in softmax, keeps e^s in f16
    }
    {
        int ch = l >> 3, i0 = (l & 7) * 4;
        int cc = g * 16 + ch;
        float mu = sqkv[cc] * (1.0f / 65536.0f);
        float var = sqkv[128 + cc] * (1.0f / 65536.0f) - mu * mu;
        float aa = bqg[cc] * rsqrtf(var + 1e-5f);
        float bb = bqb[cc] - mu * aa;
        int cv = g * 16 + 8 + ch;
        float muv = sqkv[cv] * (1.0f / 65536.0f);
        float varv = sqkv[128 + cv] * (1.0f / 65536.0f) - muv * muv;
        float av = bqg[cv] * rsqrtf(varv + 1e-5f);
        float bv = bqb[cv] - muv * av;
        #pragma unroll
        for (int pr = 0; pr < 2; ++pr) {
            int n = pr ? n1 : n0;
            int b_ = n >> 10, hw = n & 1023;
            const f16* qn = qkv + (size_t)b_ * 4194304 + (size_t)(g * 16) * 32768 + hw * 32;
            uint2 q2 = *(const uint2*)(qn + (size_t)ch * 32768 + i0);
            f16x2 p0 = u2h(q2.x), p1 = u2h(q2.y);
            qkh[pr][wv][(i0 + 0) * 8 + ch] = (f16)(aa * (float)p0.x + bb);
            qkh[pr][wv][(i0 + 1) * 8 + ch] = (f16)(aa * (float)p0.y + bb);
            qkh[pr][wv][(i0 + 2) * 8 + ch] = (f16)(aa * (float)p1.x + bb);
            qkh[pr][wv][(i0 + 3) * 8 + ch] = (f16)(aa * (float)p1.y + bb);
            uint2 v2q = *(const uint2*)(qn + (size_t)(8 + ch) * 32768 + i0);
            f16x2 v0 = u2h(v2q.x), v1q = u2h(v2q.y);
            vh[pr][wv][ch * 36 + i0 + 0] = (f16)(av * (float)v0.x + bv);
            vh[pr][wv][ch * 36 + i0 + 1] = (f16)(av * (float)v0.y + bv);
            vh[pr][wv][ch * 36 + i0 + 2] = (f16)(av * (float)v1q.x + bv);
            vh[pr][wv][ch * 36 + i0 + 3] = (f16)(av * (float)v1q.y + bv);
        }
    }
    __syncthreads();
    // ---- qk fragments (coalesced table reads), then MFMA per pair ----
    unsigned uq[2][2][4], uk[2][2][4];
    #pragma unroll
    for (int s = 0; s < 2; ++s) {
        #pragma unroll
        for (int blk = 0; blk < 2; ++blk) {
            int p0 = 16 * s + 4 * h + 8 * blk;
            unsigned tq0[4], tq1[4], tk0[4], tk1[4];
            #pragma unroll
            for (int e = 0; e < 4; ++e) {
                int rowo = (p0 + e) * 36 + li;
                tq0[e] = eTf[0 * 1152 + rowo];
                tq1[e] = eTf[1 * 1152 + rowo];
                tk0[e] = eTf[2 * 1152 + rowo];
                tk1[e] = eTf[3 * 1152 + rowo];
            }
            #pragma unroll
            for (int pr = 0; pr < 2; ++pr) {
                float qe[4], ke[4];
                #pragma unroll
                for (int e = 0; e < 4; ++e) {
                    U4 qr = ld4((const unsigned*)&qkh[pr][wv][(p0 + e) * 8]);
                    qe[e] = fdot2u(qr.a[0], tq0[e], fdot2u(qr.a[1], tq1[e], 0.f));
                    ke[e] = fdot2u(qr.a[2], tk0[e], fdot2u(qr.a[3], tk1[e], 0.f));
                }
                uq[pr][s][2 * blk + 0] = pkrtz(qe[0], qe[1]);
                uq[pr][s][2 * blk + 1] = pkrtz(qe[2], qe[3]);
                uk[pr][s][2 * blk + 0] = pkrtz(ke[0], ke[1]);
                uk[pr][s][2 * blk + 1] = pkrtz(ke[2], ke[3]);
            }
        }
    }
    f32x16 Dq0 = {}, Dq1 = {};
    {
        F8 fq0, fq1, fk0, fk1;
        #pragma unroll
        for (int j = 0; j < 4; ++j) {
            fq0.u[j] = uq[0][0][j]; fq1.u[j] = uq[0][1][j];
            fk0.u[j] = uk[0][0][j]; fk1.u[j] = uk[0][1][j];
        }
        Dq0 = __builtin_amdgcn_mfma_f32_32x32x16_f16(fk0.v, fq0.v, Dq0, 0, 0, 0);
        Dq0 = __builtin_amdgcn_mfma_f32_32x32x16_f16(fk1.v, fq1.v, Dq0, 0, 0, 0);
        #pragma unroll
        for (int j = 0; j < 4; ++j) {
            fq0.u[j] = uq[1][0][j]; fq1.u[j] = uq[1][1][j];
            fk0.u[j] = uk[1][0][j]; fk1.u[j] = uk[1][1][j];
        }
        Dq1 = __builtin_amdgcn_mfma_f32_32x32x16_f16(fk0.v, fq0.v, Dq1, 0, 0, 0);
        Dq1 = __builtin_amdgcn_mfma_f32_32x32x16_f16(fk1.v, fq1.v, Dq1, 0, 0, 0);
    }
    // ---- scores + softmax (coalesced eSc reads; packed-f16 P) ----
    U4 qhv0 = ld4((const unsigned*)&qkh[0][wv][li * 8]);
    U4 qhv1 = ld4((const unsigned*)&qkh[1][wv][li * 8]);
    unsigned up0[8], up1[8];
    float se0 = 0, se1 = 0;
    const unsigned one2 = 0x3C003C00u;
    #pragma unroll
    for (int rq = 0; rq < 4; ++rq) {
        int j0 = 8 * rq + 4 * h;
        unsigned ta0[4], ta1[4], ta2[4], ta3[4];
        #pragma unroll
        for (int e = 0; e < 4; ++e) {
            int rowo = (j0 + e) * 36 + li;
            ta0[e] = eSc[0 * 1152 + rowo];
            ta1[e] = eSc[1 * 1152 + rowo];
            ta2[e] = eSc[2 * 1152 + rowo];
            ta3[e] = eSc[3 * 1152 + rowo];
        }
        float ev0[4], ev1[4];
        #pragma unroll
        for (int e = 0; e < 4; ++e) {
            float qe4 = fdot2u(qhv0.a[0], ta0[e], fdot2u(qhv0.a[1], ta1[e], 0.f));
            float ke4 = fdot2u(qhv0.a[2], ta2[e], fdot2u(qhv0.a[3], ta3[e], 0.f));
            ev0[e] = __expf(aQK * Dq0[4 * rq + e] + aQE * qe4 + aKE * ke4 + csum);
            qe4 = fdot2u(qhv1.a[0], ta0[e], fdot2u(qhv1.a[1], ta1[e], 0.f));
            ke4 = fdot2u(qhv1.a[2], ta2[e], fdot2u(qhv1.a[3], ta3[e], 0.f));
            ev1[e] = __expf(aQK * Dq1[4 * rq + e] + aQE * qe4 + aKE * ke4 + csum);
        }
        up0[2 * rq] = pkrtz(ev0[0], ev0[1]); up0[2 * rq + 1] = pkrtz(ev0[2], ev0[3]);
        up1[2 * rq] = pkrtz(ev1[0], ev1[1]); up1[2 * rq + 1] = pkrtz(ev1[2], ev1[3]);
        se0 = fdot2u(up0[2 * rq], one2, se0); se0 = fdot2u(up0[2 * rq + 1], one2, se0);
        se1 = fdot2u(up1[2 * rq], one2, se1); se1 = fdot2u(up1[2 * rq + 1], one2, se1);
    }
    se0 += __shfl_xor(se0, 32);
    se1 += __shfl_xor(se1, 32);
    float iv0 = __frcp_rn(se0), iv1 = __frcp_rn(se1);
    unsigned hi0 = pkrtz(iv0, iv0), hi1 = pkrtz(iv1, iv1);
    #pragma unroll
    for (int w2 = 0; w2 < 8; ++w2) { up0[w2] = pkmul(up0[w2], hi0); up1[w2] = pkmul(up1[w2], hi1); }
    // ---- PV via MFMA per pair ----
    f32x16 D20 = {}, D21 = {};
    #pragma unroll
    for (int pr = 0; pr < 2; ++pr) {
        F8 fp0, fp1, fv0, fv1;
        const unsigned* up = pr ? up1 : up0;
        fp0.u[0] = up[0]; fp0.u[1] = up[1]; fp0.u[2] = up[2]; fp0.u[3] = up[3];
        fp1.u[0] = up[4]; fp1.u[1] = up[5]; fp1.u[2] = up[6]; fp1.u[3] = up[7];
        const f16* vb = &vh[pr][wv][(li & 7) * 36];
        uint2 va0 = *(const uint2*)(vb + 4 * h);
        uint2 vb0 = *(const uint2*)(vb + 4 * h + 8);
        uint2 va1 = *(const uint2*)(vb + 16 + 4 * h);
        uint2 vb1 = *(const uint2*)(vb + 16 + 4 * h + 8);
        if (li >= 8) {
            va0 = make_uint2(0, 0); vb0 = make_uint2(0, 0);
            va1 = make_uint2(0, 0); vb1 = make_uint2(0, 0);
        }
        fv0.u[0] = va0.x; fv0.u[1] = va0.y; fv0.u[2] = vb0.x; fv0.u[3] = vb0.y;
        fv1.u[0] = va1.x; fv1.u[1] = va1.y; fv1.u[2] = vb1.x; fv1.u[3] = vb1.y;
        if (pr == 0) {
            D20 = __builtin_amdgcn_mfma_f32_32x32x16_f16(fv0.v, fp0.v, D20, 0, 0, 0);
            D20 = __builtin_amdgcn_mfma_f32_32x32x16_f16(fv1.v, fp1.v, D20, 0, 0, 0);
        } else {
            D21 = __builtin_amdgcn_mfma_f32_32x32x16_f16(fv0.v, fp0.v, D21, 0, 0, 0);
            D21 = __builtin_amdgcn_mfma_f32_32x32x16_f16(fv1.v, fp1.v, D21, 0, 0, 0);
        }
    }
    // ---- ame via dot2 (shared ePv loads) ----
    float ame0[8], ame1[8];
    #pragma unroll
    for (int c = 0; c < 8; ++c) {
        const f16* er = ePvh + (c * 32 + li) * 36;
        float a0c = 0, a1c = 0;
        #pragma unroll
        for (int s = 0; s < 2; ++s) {
            #pragma unroll
            for (int dd = 0; dd < 2; ++dd) {
                uint2 ev = *(const uint2*)(er + 16 * s + 8 * dd + 4 * h);
                int widx = 4 * s + 2 * dd;
                a0c = fdot2u(up0[widx], ev.x, a0c);
                a0c = fdot2u(up0[widx + 1], ev.y, a0c);
                a1c = fdot2u(up1[widx], ev.x, a1c);
                a1c = fdot2u(up1[widx + 1], ev.y, a1c);
            }
        }
        ame0[c] = a0c + __shfl_xor(a0c, 32);
        ame1[c] = a1c + __shfl_xor(a1c, 32);
    }
    // ---- write oraw (f16) + combined out stats ----
    f16* on0 = oraw + (size_t)n0 * 4096 + g * 512;
    f16* on1 = oraw + (size_t)n1 * 4096 + g * 512;
    #pragma unroll
    for (int e = 0; e < 4; ++e) {
        int c = e + 4 * h;
        float av0 = D20[e], av1 = D21[e];
        float ae0 = ame0[c], ae1 = ame1[c];
        on0[(2 * c) * 32 + li] = (f16)av0;
        on0[(2 * c + 1) * 32 + li] = (f16)ae0;
        on1[(2 * c) * 32 + li] = (f16)av1;
        on1[(2 * c + 1) * 32 + li] = (f16)ae1;
        float x1 = sum32(av0 + av1), x2 = sum32(av0 * av0 + av1 * av1);
        float y1 = sum32(ae0 + ae1), y2 = sum32(ae0 * ae0 + ae1 * ae1);
        if (li == 0) {
            statw[wv][(2 * c) * 2 + 0] = x1;     statw[wv][(2 * c) * 2 + 1] = x2;
            statw[wv][(2 * c + 1) * 2 + 0] = y1; statw[wv][(2 * c + 1) * 2 + 1] = y2;
        }
    }
    __syncthreads();
    if (t < 32) {
        float tot = statw[0][t] + statw[1][t] + statw[2][t] + statw[3][t];
        int u = t >> 1;
        int och = g * 16 + u;
        atomicAdd(&sout[((t & 1) ? 128 : 0) + och], tot);
    }
}

// ---------------- K5: out BN + pair-sum + transpose ----------------
__global__ __launch_bounds__(256) void k_out(const f16* __restrict__ oraw,
                                             const float* __restrict__ sout,
                                             const float* __restrict__ bog,
                                             const float* __restrict__ bob,
                                             float* __restrict__ out) {
    int gid = blockIdx.x * 256 + threadIdx.x;
    int l4 = gid & 7;
    int rest = gid >> 3;
    int w2 = rest & 31; rest >>= 5;
    int hh = rest & 31; rest >>= 5;
    int oc = rest & 63;
    int b = rest >> 6;
    int n = b * 1024 + hh * 32 + w2;
    int c0 = 2 * oc, c1 = 2 * oc + 1;
    float mu0 = sout[c0] * (1.0f / 65536.0f);
    float v0 = sout[128 + c0] * (1.0f / 65536.0f) - mu0 * mu0;
    float a0 = bog[c0] * rsqrtf(v0 + 1e-5f);
    float b0 = bob[c0] - mu0 * a0;
    float mu1 = sout[c1] * (1.0f / 65536.0f);
    float v1 = sout[128 + c1] * (1.0f / 65536.0f) - mu1 * mu1;
    float a1 = bog[c1] * rsqrtf(v1 + 1e-5f);
    float b1 = bob[c1] - mu1 * a1;
    float cc = b0 + b1;
    const f16* on = oraw + (size_t)n * 4096;
    uint2 r0 = *(const uint2*)(on + oc * 64 + l4 * 4);
    uint2 r1 = *(const uint2*)(on + oc * 64 + 32 + l4 * 4);
    f16x2 r0a = u2h(r0.x), r0b = u2h(r0.y);
    f16x2 r1a = u2h(r1.x), r1b = u2h(r1.y);
    float4 o;
    o.x = a0 * (float)r0a.x + a1 * (float)r1a.x + cc;
    o.y = a0 * (float)r0a.y + a1 * (float)r1a.y + cc;
    o.z = a0 * (float)r0b.x + a1 * (float)r1b.x + cc;
    o.w = a0 * (float)r0b.y + a1 * (float)r1b.y + cc;
    *((float4*)out + gid) = o;
}

extern "C" void kernel_launch(void* const* d_in, const int* in_sizes, int n_in,
                              void* d_out, int out_size, void* d_ws, size_t ws_size,
                              hipStream_t stream) {
    const float* x   = (const float*)d_in[0];
    const float* w   = (const float*)d_in[1];
    const float* bqg = (const float*)d_in[2];
    const float* bqb = (const float*)d_in[3];
    const float* bsg = (const float*)d_in[4];
    const float* bsb = (const float*)d_in[5];
    const float* bog = (const float*)d_in[6];
    const float* bob = (const float*)d_in[7];
    const float* rel = (const float*)d_in[8];

    f16* qkv16  = (f16*)d_ws;                       // 16 MB (8,388,608 halves)
    f16* oraw16 = qkv16 + 8388608;                  // 16 MB
    f16* gemb   = oraw16 + 8388608;                 // 55 KB (27,648 halves)
    float* stats = (float*)(gemb + 27648);
    float* sqkv = stats;        // 256
    float* ssim = stats + 256;  // 48
    float* sout = stats + 304;  // 256
    float* pq   = stats + 576;                      // 1 MB (1024*256 f32)
    float* psim = (float*)oraw16;   // overlap: consumed by red_sim before k_attn writes oraw

    hipMemsetAsync(stats, 0, 560 * sizeof(float), stream);

    k_qkv<<<1024, 256, 0, stream>>>(x, w, qkv16, pq);
    red_qkv<<<16, 256, 0, stream>>>(pq, sqkv, rel, gemb);
    k_sim<<<1024, 512, 0, stream>>>(qkv16, gemb, sqkv, bqg, bqb, psim);
    red_sim<<<1, 64, 0, stream>>>(psim, ssim);
    k_attn<<<2048, 256, 0, stream>>>(qkv16, gemb, sqkv, bqg, bqb, ssim, bsg, bsb, oraw16, sout);
    k_out<<<4096, 256, 0, stream>>>(oraw16, sout, bog, bob, (float*)d_out);
}

// Round 15
// 87.445 us; speedup vs baseline: 1.2214x; 1.0527x over previous
//
#include <hip/hip_runtime.h>

// x: (2,64,32,32,32) f32; N = 2048 rows of (C=64, L=32)
// qkv(f16): [b][och][32768]; oraw(f16): (N,128,32)
// MFMA convention (validated r3-r14): mfma_f32_32x32x16_f16(A,B,C):
//   A-frag: lane&31 = row m, k = (e&3)+4*(lane>>5)+8*(e>>2)+16*ks
//   B-frag: lane&31 = col n, same k pattern
//   D: col = lane&31, row = (r&3)+8*(r>>2)+4*(lane>>5)
// Partitioning (r11/r14 proven): k_sim 1024x512; k_attn 2048x256; 2 pairs/wave.
// r14: eT2/eP2 are each other's transposes -> all frag/score table reads
// coalesced (b32 lane-consecutive). r15: ame tables j-pair packed (ePvJ)
// -> coalesced too; exp2f with folded log2e coefficients.
// r9: qk round-trip loses to recompute. r12: coop-launch occupancy trap.
// r13: >2 pairs/wave spills.

typedef _Float16 f16;
typedef __attribute__((ext_vector_type(2))) _Float16 f16x2;
typedef __attribute__((ext_vector_type(8))) _Float16 f16x8;
typedef __attribute__((ext_vector_type(16))) float f32x16;

struct U4 { unsigned a[4]; };
union F8 { unsigned u[4]; f16x8 v; };

__device__ __forceinline__ U4 ld4(const unsigned* p) {
    uint4 v = *(const uint4*)p;
    U4 r; r.a[0] = v.x; r.a[1] = v.y; r.a[2] = v.z; r.a[3] = v.w;
    return r;
}
__device__ __forceinline__ f16x2 u2h(unsigned u) { return __builtin_bit_cast(f16x2, u); }

__device__ __forceinline__ float fdot2u(unsigned a, unsigned b, float c) {
#if __has_builtin(__builtin_amdgcn_fdot2)
    return __builtin_amdgcn_fdot2(u2h(a), u2h(b), c, false);
#else
    f16x2 x = u2h(a), y = u2h(b);
    return (float)x.x * (float)y.x + (float)x.y * (float)y.y + c;
#endif
}
__device__ __forceinline__ unsigned pkrtz(float a, float b) {
#if __has_builtin(__builtin_amdgcn_cvt_pkrtz)
    return __builtin_bit_cast(unsigned, __builtin_amdgcn_cvt_pkrtz(a, b));
#else
    f16x2 v; v.x = (f16)a; v.y = (f16)b;
    return __builtin_bit_cast(unsigned, v);
#endif
}
__device__ __forceinline__ unsigned pkmul(unsigned a, unsigned b) {
    f16x2 x = u2h(a), y = u2h(b);
    f16x2 r = x * y;
    return __builtin_bit_cast(unsigned, r);
}

__device__ __forceinline__ float sum16(float v) {
    int x;
    x = __builtin_amdgcn_update_dpp(0, __float_as_int(v), 0x121, 0xF, 0xF, true); v += __int_as_float(x);
    x = __builtin_amdgcn_update_dpp(0, __float_as_int(v), 0x122, 0xF, 0xF, true); v += __int_as_float(x);
    x = __builtin_amdgcn_update_dpp(0, __float_as_int(v), 0x124, 0xF, 0xF, true); v += __int_as_float(x);
    x = __builtin_amdgcn_update_dpp(0, __float_as_int(v), 0x128, 0xF, 0xF, true); v += __int_as_float(x);
    return v;
}
__device__ __forceinline__ float sum32(float v) {
    v = sum16(v); return v + __shfl_xor(v, 16);
}
__device__ __forceinline__ float sum64(float v) {
    v = sum16(v); v += __shfl_xor(v, 16); return v + __shfl_xor(v, 32);
}

// ---------------- K1: qkv = W @ X GEMM via MFMA, LDS-staged ----------------
__global__ __launch_bounds__(256) void k_qkv(const float* __restrict__ x,
                                             const float* __restrict__ w,
                                             f16* __restrict__ qkv,
                                             float* __restrict__ pq) {
    __shared__ __attribute__((aligned(16))) unsigned xt[32 * 66];
    int t = threadIdx.x, wv = t >> 6, l = t & 63;
    int li = l & 31, h = l >> 5;
    int bid = blockIdx.x;
    int b = bid >> 9;
    int col0 = (bid & 511) * 64;
    const float* xb = x + (size_t)b * 2097152 + col0;
    #pragma unroll
    for (int k = 0; k < 4; ++k) {
        int idx = t + 256 * k;
        int col2 = idx & 31, p = idx >> 5;
        const float* r0 = xb + (size_t)(2 * p) * 32768 + 2 * col2;
        float2 a = *(const float2*)r0;
        float2 bb = *(const float2*)(r0 + 32768);
        int ks = p >> 3, hh = (p >> 1) & 1, m = (p & 1) + 2 * ((p >> 2) & 1);
        unsigned w0 = pkrtz(a.x, bb.x);
        unsigned w1 = pkrtz(a.y, bb.y);
        *(uint2*)&xt[(ks * 8 + hh * 4 + m) * 66 + 2 * col2] = make_uint2(w0, w1);
    }
    f16x8 aw[4];
    {
        const float* wr = w + (size_t)(32 * wv + li) * 64;
        #pragma unroll
        for (int ks = 0; ks < 4; ++ks) {
            float4 w0 = *(const float4*)(wr + 16 * ks + 4 * h);
            float4 w1 = *(const float4*)(wr + 16 * ks + 8 + 4 * h);
            F8 fa;
            fa.u[0] = pkrtz(w0.x, w0.y); fa.u[1] = pkrtz(w0.z, w0.w);
            fa.u[2] = pkrtz(w1.x, w1.y); fa.u[3] = pkrtz(w1.z, w1.w);
            aw[ks] = fa.v;
        }
    }
    __syncthreads();
    float s1a[16] = {}, s2a[16] = {};
    #pragma unroll
    for (int ct = 0; ct < 2; ++ct) {
        f32x16 D = {};
        #pragma unroll
        for (int ks = 0; ks < 4; ++ks) {
            F8 fb;
            #pragma unroll
            for (int m = 0; m < 4; ++m)
                fb.u[m] = xt[(ks * 8 + h * 4 + m) * 66 + ct * 32 + li];
            D = __builtin_amdgcn_mfma_f32_32x32x16_f16(aw[ks], fb.v, D, 0, 0, 0);
        }
        int colg = col0 + ct * 32 + li;
        f16* qn = qkv + (size_t)b * 4194304 + colg;
        #pragma unroll
        for (int r = 0; r < 16; ++r) {
            int och = 32 * wv + (r & 3) + 8 * (r >> 2) + 4 * h;
            qn[(size_t)och * 32768] = (f16)D[r];
            s1a[r] += D[r];
            s2a[r] += D[r] * D[r];
        }
    }
    #pragma unroll
    for (int r = 0; r < 16; ++r) {
        float s1 = sum32(s1a[r]);
        float s2 = sum32(s2a[r]);
        if (li == 0) {
            int och = 32 * wv + (r & 3) + 8 * (r >> 2) + 4 * h;
            pq[(size_t)bid * 256 + och * 2] = s1;
            pq[(size_t)bid * 256 + och * 2 + 1] = s2;
        }
    }
}

// ---------------- K1b: reduce qkv-stat partials + build f16 emb tables -------
// gemb layout (halves): eT2 [0,9216) | eP2 [9216,18432) | ePvJ [18432,26624)
//   ePvJ word w at (c*16+j2)*32+i packs (rel[8+c][i-2j2+31], rel[8+c][i-2j2+30])
__global__ __launch_bounds__(256) void red_qkv(const float* __restrict__ pq,
                                               float* __restrict__ sqkv,
                                               const float* __restrict__ rel,
                                               f16* __restrict__ gemb) {
    int t = threadIdx.x;
    int base = blockIdx.x * 64;
    float acc = 0;
    #pragma unroll 8
    for (int k = 0; k < 64; ++k) acc += pq[(size_t)(base + k) * 256 + t];
    atomicAdd(&sqkv[((t & 1) ? 128 : 0) + (t >> 1)], acc);
    int tid = blockIdx.x * 256 + t;
    for (int e = tid; e < 4608; e += 4096) {         // eT2 [c2][y][x]=rel[x-y+31]
        int c2 = e / 1152, rm = e % 1152, y = rm / 36, x = rm % 36;
        f16 v0 = (f16)0, v1 = (f16)0;
        if (x < 32) {
            v0 = (f16)rel[(2 * c2) * 63 + x - y + 31];
            v1 = (f16)rel[(2 * c2 + 1) * 63 + x - y + 31];
        }
        gemb[2 * e] = v0; gemb[2 * e + 1] = v1;
    }
    for (int e = tid; e < 4608; e += 4096) {         // eP2 [c2][a][b]=rel[a-b+31]
        int c2 = e / 1152, rm = e % 1152, a = rm / 36, b = rm % 36;
        f16 v0 = (f16)0, v1 = (f16)0;
        if (b < 32) {
            v0 = (f16)rel[(2 * c2) * 63 + a - b + 31];
            v1 = (f16)rel[(2 * c2 + 1) * 63 + a - b + 31];
        }
        gemb[9216 + 2 * e] = v0; gemb[9216 + 2 * e + 1] = v1;
    }
    for (int e = tid; e < 4096; e += 4096) {         // ePvJ (j-pair packed)
        int c = e >> 9, rm = e & 511, j2 = rm >> 5, i = rm & 31;
        int d0 = i - 2 * j2 + 31;
        gemb[18432 + 2 * e]     = (f16)rel[(8 + c) * 63 + d0];
        gemb[18432 + 2 * e + 1] = (f16)rel[(8 + c) * 63 + d0 - 1];
    }
}

// ---------------- K2: sim stats (512 thr, 1024 blocks; coalesced tables) ------
__global__ __launch_bounds__(512, 2) void k_sim(const f16* __restrict__ qkv,
                                                const f16* __restrict__ gemb,
                                                const float* __restrict__ sqkv,
                                                const float* __restrict__ bqg,
                                                const float* __restrict__ bqb,
                                                float* __restrict__ psim) {
    __shared__ __attribute__((aligned(16))) f16 qkh[2][8][256];
    __shared__ float statw[8][6];
    int t = threadIdx.x, wv = t >> 6, l = t & 63;
    int g = blockIdx.x & 7, nb = blockIdx.x >> 3;   // nb in [0,128)
    int li = l & 31, h = l >> 5;
    const unsigned* eTf = (const unsigned*)gemb + 4608;  // eP2 region (transposed read)
    {
        int ch = l >> 3, i0 = (l & 7) * 4;
        int cc = g * 16 + ch;
        float mu = sqkv[cc] * (1.0f / 65536.0f);
        float var = sqkv[128 + cc] * (1.0f / 65536.0f) - mu * mu;
        float aa = bqg[cc] * rsqrtf(var + 1e-5f);
        float bb = bqb[cc] - mu * aa;
        #pragma unroll
        for (int pr = 0; pr < 2; ++pr) {
            int n = nb * 8 + wv + pr * 1024;
            int b_ = n >> 10, hw = n & 1023;
            const f16* qn = qkv + (size_t)b_ * 4194304 + (size_t)(g * 16) * 32768 + hw * 32;
            uint2 q2 = *(const uint2*)(qn + (size_t)ch * 32768 + i0);
            f16x2 p0 = u2h(q2.x), p1 = u2h(q2.y);
            qkh[pr][wv][(i0 + 0) * 8 + ch] = (f16)(aa * (float)p0.x + bb);
            qkh[pr][wv][(i0 + 1) * 8 + ch] = (f16)(aa * (float)p0.y + bb);
            qkh[pr][wv][(i0 + 2) * 8 + ch] = (f16)(aa * (float)p1.x + bb);
            qkh[pr][wv][(i0 + 3) * 8 + ch] = (f16)(aa * (float)p1.y + bb);
        }
    }
    __syncthreads();
    unsigned uq[2][2][4], uk[2][2][4];
    float sqe = 0, sqe2 = 0, ske = 0, ske2 = 0;
    #pragma unroll
    for (int s = 0; s < 2; ++s) {
        #pragma unroll
        for (int blk = 0; blk < 2; ++blk) {
            int p0 = 16 * s + 4 * h + 8 * blk;
            unsigned tq0[4], tq1[4], tk0[4], tk1[4];
            #pragma unroll
            for (int e = 0; e < 4; ++e) {             // coalesced: stride-1 in li
                int rowo = (p0 + e) * 36 + li;
                tq0[e] = eTf[0 * 1152 + rowo];
                tq1[e] = eTf[1 * 1152 + rowo];
                tk0[e] = eTf[2 * 1152 + rowo];
                tk1[e] = eTf[3 * 1152 + rowo];
            }
            #pragma unroll
            for (int pr = 0; pr < 2; ++pr) {
                float qe[4], ke[4];
                #pragma unroll
                for (int e = 0; e < 4; ++e) {
                    U4 qr = ld4((const unsigned*)&qkh[pr][wv][(p0 + e) * 8]);
                    qe[e] = fdot2u(qr.a[0], tq0[e], fdot2u(qr.a[1], tq1[e], 0.f));
                    ke[e] = fdot2u(qr.a[2], tk0[e], fdot2u(qr.a[3], tk1[e], 0.f));
                    sqe += qe[e]; sqe2 += qe[e] * qe[e];
                    ske += ke[e]; ske2 += ke[e] * ke[e];
                }
                uq[pr][s][2 * blk + 0] = pkrtz(qe[0], qe[1]);
                uq[pr][s][2 * blk + 1] = pkrtz(qe[2], qe[3]);
                uk[pr][s][2 * blk + 0] = pkrtz(ke[0], ke[1]);
                uk[pr][s][2 * blk + 1] = pkrtz(ke[2], ke[3]);
            }
        }
    }
    float s1 = 0, s2 = 0;
    #pragma unroll
    for (int pr = 0; pr < 2; ++pr) {
        F8 fq0, fq1, fk0, fk1;
        #pragma unroll
        for (int j = 0; j < 4; ++j) {
            fq0.u[j] = uq[pr][0][j]; fq1.u[j] = uq[pr][1][j];
            fk0.u[j] = uk[pr][0][j]; fk1.u[j] = uk[pr][1][j];
        }
        f32x16 D = {};
        D = __builtin_amdgcn_mfma_f32_32x32x16_f16(fk0.v, fq0.v, D, 0, 0, 0);
        D = __builtin_amdgcn_mfma_f32_32x32x16_f16(fk1.v, fq1.v, D, 0, 0, 0);
        #pragma unroll
        for (int r = 0; r < 16; ++r) { s1 += D[r]; s2 += D[r] * D[r]; }
    }
    s1 = sum64(s1);   s2 = sum64(s2);
    sqe = sum64(sqe); sqe2 = sum64(sqe2);
    ske = sum64(ske); ske2 = sum64(ske2);
    if (l == 0) {
        statw[wv][0] = s1;  statw[wv][1] = s2;
        statw[wv][2] = sqe; statw[wv][3] = sqe2;
        statw[wv][4] = ske; statw[wv][5] = ske2;
    }
    __syncthreads();
    if (t < 6) {
        float tot = 0;
        #pragma unroll
        for (int w2 = 0; w2 < 8; ++w2) tot += statw[w2][t];
        psim[blockIdx.x * 8 + t] = tot;
    }
}

// ---------------- K3: reduce sim partials ----------------
__global__ __launch_bounds__(64) void red_sim(const float* __restrict__ psim,
                                              float* __restrict__ ssim) {
    int t = threadIdx.x;
    if (t >= 48) return;
    int g = t / 6, s = t % 6;
    float acc = 0;
    #pragma unroll 8
    for (int nb = 0; nb < 128; ++nb) acc += psim[(nb * 8 + g) * 8 + s];
    const int base[6] = {0, 24, 8, 32, 16, 40};
    ssim[base[s] + g] = acc;
}

// ---------------- K4: attention (2048 x 256, 2 pairs/wave, all-coalesced) -----
__global__ __launch_bounds__(256, 4) void k_attn(const f16* __restrict__ qkv,
                                                 const f16* __restrict__ gemb,
                                                 const float* __restrict__ sqkv,
                                                 const float* __restrict__ bqg,
                                                 const float* __restrict__ bqb,
                                                 const float* __restrict__ ssim,
                                                 const float* __restrict__ bsg,
                                                 const float* __restrict__ bsb,
                                                 f16* __restrict__ oraw,
                                                 float* __restrict__ sout) {
    __shared__ __attribute__((aligned(16))) f16 qkh[2][4][256];
    __shared__ __attribute__((aligned(16))) f16 vh[2][4][288];
    __shared__ float statw[4][32];
    int t = threadIdx.x, wv = t >> 6, l = t & 63;
    int g = blockIdx.x & 7, nb = blockIdx.x >> 3;   // nb in [0,256)
    int li = l & 31, h = l >> 5;
    const unsigned* eTf = (const unsigned*)gemb + 4608;  // frag: eP2 region
    const unsigned* eSc = (const unsigned*)gemb;         // score: eT2 region
    const unsigned* ePvJ = (const unsigned*)gemb + 9216; // ame: j-pair packed
    int n0 = nb * 4 + wv, n1 = n0 + 1024;
    float aQK, aQE, aKE, csum;
    {
        const float LOG2E = 1.4426950408889634f;
        float m0 = ssim[g] * (1.0f / 2097152.0f);
        float v0 = ssim[24 + g] * (1.0f / 2097152.0f) - m0 * m0;
        aQK = bsg[g] * rsqrtf(v0 + 1e-5f);
        float b0 = bsb[g] - m0 * aQK;
        float m1 = ssim[8 + g] * (1.0f / 2097152.0f);
        float v1 = ssim[32 + g] * (1.0f / 2097152.0f) - m1 * m1;
        aQE = bsg[8 + g] * rsqrtf(v1 + 1e-5f);
        float b1 = bsb[8 + g] - m1 * aQE;
        float m2 = ssim[16 + g] * (1.0f / 2097152.0f);
        float v2 = ssim[40 + g] * (1.0f / 2097152.0f) - m2 * m2;
        aKE = bsg[16 + g] * rsqrtf(v2 + 1e-5f);
        float b2 = bsb[16 + g] - m2 * aKE;
        csum = (b0 + b1 + b2 - 6.0f) * LOG2E;  // -6 bias cancels in softmax; log2e folded
        aQK *= LOG2E; aQE *= LOG2E; aKE *= LOG2E;
    }
    {
        int ch = l >> 3, i0 = (l & 7) * 4;
        int cc = g * 16 + ch;
        float mu = sqkv[cc] * (1.0f / 65536.0f);
        float var = sqkv[128 + cc] * (1.0f / 65536.0f) - mu * mu;
        float aa = bqg[cc] * rsqrtf(var + 1e-5f);
        float bb = bqb[cc] - mu * aa;
        int cv = g * 16 + 8 + ch;
        float muv = sqkv[cv] * (1.0f / 65536.0f);
        float varv = sqkv[128 + cv] * (1.0f / 65536.0f) - muv * muv;
        float av = bqg[cv] * rsqrtf(varv + 1e-5f);
        float bv = bqb[cv] - muv * av;
        #pragma unroll
        for (int pr = 0; pr < 2; ++pr) {
            int n = pr ? n1 : n0;
            int b_ = n >> 10, hw = n & 1023;
            const f16* qn = qkv + (size_t)b_ * 4194304 + (size_t)(g * 16) * 32768 + hw * 32;
            uint2 q2 = *(const uint2*)(qn + (size_t)ch * 32768 + i0);
            f16x2 p0 = u2h(q2.x), p1 = u2h(q2.y);
            qkh[pr][wv][(i0 + 0) * 8 + ch] = (f16)(aa * (float)p0.x + bb);
            qkh[pr][wv][(i0 + 1) * 8 + ch] = (f16)(aa * (float)p0.y + bb);
            qkh[pr][wv][(i0 + 2) * 8 + ch] = (f16)(aa * (float)p1.x + bb);
            qkh[pr][wv][(i0 + 3) * 8 + ch] = (f16)(aa * (float)p1.y + bb);
            uint2 v2q = *(const uint2*)(qn + (size_t)(8 + ch) * 32768 + i0);
            f16x2 v0 = u2h(v2q.x), v1q = u2h(v2q.y);
            vh[pr][wv][ch * 36 + i0 + 0] = (f16)(av * (float)v0.x + bv);
            vh[pr][wv][ch * 36 + i0 + 1] = (f16)(av * (float)v0.y + bv);
            vh[pr][wv][ch * 36 + i0 + 2] = (f16)(av * (float)v1q.x + bv);
            vh[pr][wv][ch * 36 + i0 + 3] = (f16)(av * (float)v1q.y + bv);
        }
    }
    __syncthreads();
    // ---- qk fragments (coalesced table reads), then MFMA per pair ----
    unsigned uq[2][2][4], uk[2][2][4];
    #pragma unroll
    for (int s = 0; s < 2; ++s) {
        #pragma unroll
        for (int blk = 0; blk < 2; ++blk) {
            int p0 = 16 * s + 4 * h + 8 * blk;
            unsigned tq0[4], tq1[4], tk0[4], tk1[4];
            #pragma unroll
            for (int e = 0; e < 4; ++e) {
                int rowo = (p0 + e) * 36 + li;
                tq0[e] = eTf[0 * 1152 + rowo];
                tq1[e] = eTf[1 * 1152 + rowo];
                tk0[e] = eTf[2 * 1152 + rowo];
                tk1[e] = eTf[3 * 1152 + rowo];
            }
            #pragma unroll
            for (int pr = 0; pr < 2; ++pr) {
                float qe[4], ke[4];
                #pragma unroll
                for (int e = 0; e < 4; ++e) {
                    U4 qr = ld4((const unsigned*)&qkh[pr][wv][(p0 + e) * 8]);
                    qe[e] = fdot2u(qr.a[0], tq0[e], fdot2u(qr.a[1], tq1[e], 0.f));
                    ke[e] = fdot2u(qr.a[2], tk0[e], fdot2u(qr.a[3], tk1[e], 0.f));
                }
                uq[pr][s][2 * blk + 0] = pkrtz(qe[0], qe[1]);
                uq[pr][s][2 * blk + 1] = pkrtz(qe[2], qe[3]);
                uk[pr][s][2 * blk + 0] = pkrtz(ke[0], ke[1]);
                uk[pr][s][2 * blk + 1] = pkrtz(ke[2], ke[3]);
            }
        }
    }
    f32x16 Dq0 = {}, Dq1 = {};
    {
        F8 fq0, fq1, fk0, fk1;
        #pragma unroll
        for (int j = 0; j < 4; ++j) {
            fq0.u[j] = uq[0][0][j]; fq1.u[j] = uq[0][1][j];
            fk0.u[j] = uk[0][0][j]; fk1.u[j] = uk[0][1][j];
        }
        Dq0 = __builtin_amdgcn_mfma_f32_32x32x16_f16(fk0.v, fq0.v, Dq0, 0, 0, 0);
        Dq0 = __builtin_amdgcn_mfma_f32_32x32x16_f16(fk1.v, fq1.v, Dq0, 0, 0, 0);
        #pragma unroll
        for (int j = 0; j < 4; ++j) {
            fq0.u[j] = uq[1][0][j]; fq1.u[j] = uq[1][1][j];
            fk0.u[j] = uk[1][0][j]; fk1.u[j] = uk[1][1][j];
        }
        Dq1 = __builtin_amdgcn_mfma_f32_32x32x16_f16(fk0.v, fq0.v, Dq1, 0, 0, 0);
        Dq1 = __builtin_amdgcn_mfma_f32_32x32x16_f16(fk1.v, fq1.v, Dq1, 0, 0, 0);
    }
    // ---- scores + softmax (coalesced eSc reads; exp2; packed-f16 P) ----
    U4 qhv0 = ld4((const unsigned*)&qkh[0][wv][li * 8]);
    U4 qhv1 = ld4((const unsigned*)&qkh[1][wv][li * 8]);
    unsigned up0[8], up1[8];
    float se0 = 0, se1 = 0;
    const unsigned one2 = 0x3C003C00u;
    #pragma unroll
    for (int rq = 0; rq < 4; ++rq) {
        int j0 = 8 * rq + 4 * h;
        unsigned ta0[4], ta1[4], ta2[4], ta3[4];
        #pragma unroll
        for (int e = 0; e < 4; ++e) {
            int rowo = (j0 + e) * 36 + li;
            ta0[e] = eSc[0 * 1152 + rowo];
            ta1[e] = eSc[1 * 1152 + rowo];
            ta2[e] = eSc[2 * 1152 + rowo];
            ta3[e] = eSc[3 * 1152 + rowo];
        }
        float ev0[4], ev1[4];
        #pragma unroll
        for (int e = 0; e < 4; ++e) {
            float qe4 = fdot2u(qhv0.a[0], ta0[e], fdot2u(qhv0.a[1], ta1[e], 0.f));
            float ke4 = fdot2u(qhv0.a[2], ta2[e], fdot2u(qhv0.a[3], ta3[e], 0.f));
            ev0[e] = exp2f(aQK * Dq0[4 * rq + e] + aQE * qe4 + aKE * ke4 + csum);
            qe4 = fdot2u(qhv1.a[0], ta0[e], fdot2u(qhv1.a[1], ta1[e], 0.f));
            ke4 = fdot2u(qhv1.a[2], ta2[e], fdot2u(qhv1.a[3], ta3[e], 0.f));
            ev1[e] = exp2f(aQK * Dq1[4 * rq + e] + aQE * qe4 + aKE * ke4 + csum);
        }
        up0[2 * rq] = pkrtz(ev0[0], ev0[1]); up0[2 * rq + 1] = pkrtz(ev0[2], ev0[3]);
        up1[2 * rq] = pkrtz(ev1[0], ev1[1]); up1[2 * rq + 1] = pkrtz(ev1[2], ev1[3]);
        se0 = fdot2u(up0[2 * rq], one2, se0); se0 = fdot2u(up0[2 * rq + 1], one2, se0);
        se1 = fdot2u(up1[2 * rq], one2, se1); se1 = fdot2u(up1[2 * rq + 1], one2, se1);
    }
    se0 += __shfl_xor(se0, 32);
    se1 += __shfl_xor(se1, 32);
    float iv0 = __frcp_rn(se0), iv1 = __frcp_rn(se1);
    unsigned hi0 = pkrtz(iv0, iv0), hi1 = pkrtz(iv1, iv1);
    #pragma unroll
    for (int w2 = 0; w2 < 8; ++w2) { up0[w2] = pkmul(up0[w2], hi0); up1[w2] = pkmul(up1[w2], hi1); }
    // ---- PV via MFMA per pair ----
    f32x16 D20 = {}, D21 = {};
    #pragma unroll
    for (int pr = 0; pr < 2; ++pr) {
        F8 fp0, fp1, fv0, fv1;
        const unsigned* up = pr ? up1 : up0;
        fp0.u[0] = up[0]; fp0.u[1] = up[1]; fp0.u[2] = up[2]; fp0.u[3] = up[3];
        fp1.u[0] = up[4]; fp1.u[1] = up[5]; fp1.u[2] = up[6]; fp1.u[3] = up[7];
        const f16* vb = &vh[pr][wv][(li & 7) * 36];
        uint2 va0 = *(const uint2*)(vb + 4 * h);
        uint2 vb0 = *(const uint2*)(vb + 4 * h + 8);
        uint2 va1 = *(const uint2*)(vb + 16 + 4 * h);
        uint2 vb1 = *(const uint2*)(vb + 16 + 4 * h + 8);
        if (li >= 8) {
            va0 = make_uint2(0, 0); vb0 = make_uint2(0, 0);
            va1 = make_uint2(0, 0); vb1 = make_uint2(0, 0);
        }
        fv0.u[0] = va0.x; fv0.u[1] = va0.y; fv0.u[2] = vb0.x; fv0.u[3] = vb0.y;
        fv1.u[0] = va1.x; fv1.u[1] = va1.y; fv1.u[2] = vb1.x; fv1.u[3] = vb1.y;
        if (pr == 0) {
            D20 = __builtin_amdgcn_mfma_f32_32x32x16_f16(fv0.v, fp0.v, D20, 0, 0, 0);
            D20 = __builtin_amdgcn_mfma_f32_32x32x16_f16(fv1.v, fp1.v, D20, 0, 0, 0);
        } else {
            D21 = __builtin_amdgcn_mfma_f32_32x32x16_f16(fv0.v, fp0.v, D21, 0, 0, 0);
            D21 = __builtin_amdgcn_mfma_f32_32x32x16_f16(fv1.v, fp1.v, D21, 0, 0, 0);
        }
    }
    // ---- ame via dot2 (coalesced ePvJ reads, shared across pairs) ----
    float ame0[8], ame1[8];
    #pragma unroll
    for (int c = 0; c < 8; ++c) {
        float a0c = 0, a1c = 0;
        #pragma unroll
        for (int rq = 0; rq < 4; ++rq) {
            int j2a = 4 * rq + 2 * h;
            unsigned w0 = ePvJ[(c * 16 + j2a) * 32 + li];
            unsigned w1 = ePvJ[(c * 16 + j2a + 1) * 32 + li];
            a0c = fdot2u(up0[2 * rq], w0, a0c);
            a0c = fdot2u(up0[2 * rq + 1], w1, a0c);
            a1c = fdot2u(up1[2 * rq], w0, a1c);
            a1c = fdot2u(up1[2 * rq + 1], w1, a1c);
        }
        ame0[c] = a0c + __shfl_xor(a0c, 32);
        ame1[c] = a1c + __shfl_xor(a1c, 32);
    }
    // ---- write oraw (f16) + combined out stats ----
    f16* on0 = oraw + (size_t)n0 * 4096 + g * 512;
    f16* on1 = oraw + (size_t)n1 * 4096 + g * 512;
    #pragma unroll
    for (int e = 0; e < 4; ++e) {
        int c = e + 4 * h;
        float av0 = D20[e], av1 = D21[e];
        float ae0 = ame0[c], ae1 = ame1[c];
        on0[(2 * c) * 32 + li] = (f16)av0;
        on0[(2 * c + 1) * 32 + li] = (f16)ae0;
        on1[(2 * c) * 32 + li] = (f16)av1;
        on1[(2 * c + 1) * 32 + li] = (f16)ae1;
        float x1 = sum32(av0 + av1), x2 = sum32(av0 * av0 + av1 * av1);
        float y1 = sum32(ae0 + ae1), y2 = sum32(ae0 * ae0 + ae1 * ae1);
        if (li == 0) {
            statw[wv][(2 * c) * 2 + 0] = x1;     statw[wv][(2 * c) * 2 + 1] = x2;
            statw[wv][(2 * c + 1) * 2 + 0] = y1; statw[wv][(2 * c + 1) * 2 + 1] = y2;
        }
    }
    __syncthreads();
    if (t < 32) {
        float tot = statw[0][t] + statw[1][t] + statw[2][t] + statw[3][t];
        int u = t >> 1;
        int och = g * 16 + u;
        atomicAdd(&sout[((t & 1) ? 128 : 0) + och], tot);
    }
}

// ---------------- K5: out BN + pair-sum + transpose ----------------
__global__ __launch_bounds__(256) void k_out(const f16* __restrict__ oraw,
                                             const float* __restrict__ sout,
                                             const float* __restrict__ bog,
                                             const float* __restrict__ bob,
                                             float* __restrict__ out) {
    int gid = blockIdx.x * 256 + threadIdx.x;
    int l4 = gid & 7;
    int rest = gid >> 3;
    int w2 = rest & 31; rest >>= 5;
    int hh = rest & 31; rest >>= 5;
    int oc = rest & 63;
    int b = rest >> 6;
    int n = b * 1024 + hh * 32 + w2;
    int c0 = 2 * oc, c1 = 2 * oc + 1;
    float mu0 = sout[c0] * (1.0f / 65536.0f);
    float v0 = sout[128 + c0] * (1.0f / 65536.0f) - mu0 * mu0;
    float a0 = bog[c0] * rsqrtf(v0 + 1e-5f);
    float b0 = bob[c0] - mu0 * a0;
    float mu1 = sout[c1] * (1.0f / 65536.0f);
    float v1 = sout[128 + c1] * (1.0f / 65536.0f) - mu1 * mu1;
    float a1 = bog[c1] * rsqrtf(v1 + 1e-5f);
    float b1 = bob[c1] - mu1 * a1;
    float cc = b0 + b1;
    const f16* on = oraw + (size_t)n * 4096;
    uint2 r0 = *(const uint2*)(on + oc * 64 + l4 * 4);
    uint2 r1 = *(const uint2*)(on + oc * 64 + 32 + l4 * 4);
    f16x2 r0a = u2h(r0.x), r0b = u2h(r0.y);
    f16x2 r1a = u2h(r1.x), r1b = u2h(r1.y);
    float4 o;
    o.x = a0 * (float)r0a.x + a1 * (float)r1a.x + cc;
    o.y = a0 * (float)r0a.y + a1 * (float)r1a.y + cc;
    o.z = a0 * (float)r0b.x + a1 * (float)r1b.x + cc;
    o.w = a0 * (float)r0b.y + a1 * (float)r1b.y + cc;
    *((float4*)out + gid) = o;
}

extern "C" void kernel_launch(void* const* d_in, const int* in_sizes, int n_in,
                              void* d_out, int out_size, void* d_ws, size_t ws_size,
                              hipStream_t stream) {
    const float* x   = (const float*)d_in[0];
    const float* w   = (const float*)d_in[1];
    const float* bqg = (const float*)d_in[2];
    const float* bqb = (const float*)d_in[3];
    const float* bsg = (const float*)d_in[4];
    const float* bsb = (const float*)d_in[5];
    const float* bog = (const float*)d_in[6];
    const float* bob = (const float*)d_in[7];
    const float* rel = (const float*)d_in[8];

    f16* qkv16  = (f16*)d_ws;                       // 16 MB (8,388,608 halves)
    f16* oraw16 = qkv16 + 8388608;                  // 16 MB
    f16* gemb   = oraw16 + 8388608;                 // 55 KB (27,648 halves)
    float* stats = (float*)(gemb + 27648);
    float* sqkv = stats;        // 256
    float* ssim = stats + 256;  // 48
    float* sout = stats + 304;  // 256
    float* pq   = stats + 576;                      // 1 MB (1024*256 f32)
    float* psim = (float*)oraw16;   // overlap: consumed by red_sim before k_attn writes oraw

    hipMemsetAsync(stats, 0, 560 * sizeof(float), stream);

    k_qkv<<<1024, 256, 0, stream>>>(x, w, qkv16, pq);
    red_qkv<<<16, 256, 0, stream>>>(pq, sqkv, rel, gemb);
    k_sim<<<1024, 512, 0, stream>>>(qkv16, gemb, sqkv, bqg, bqb, psim);
    red_sim<<<1, 64, 0, stream>>>(psim, ssim);
    k_attn<<<2048, 256, 0, stream>>>(qkv16, gemb, sqkv, bqg, bqb, ssim, bsg, bsb, oraw16, sout);
    k_out<<<4096, 256, 0, stream>>>(oraw16, sout, bog, bob, (float*)d_out);
}